// Round 8
// baseline (600.113 us; speedup 1.0000x reference)
//
#include <hip/hip_runtime.h>

typedef unsigned short bf16_t;
typedef __attribute__((ext_vector_type(8))) short bf16x8;
typedef __attribute__((ext_vector_type(8))) unsigned short u16x8;
typedef __attribute__((ext_vector_type(4))) float f32x4;

#if defined(__has_builtin)
#if __has_builtin(__builtin_amdgcn_global_load_lds)
#define HAS_GLL 1
#endif
#endif

__device__ __forceinline__ float b2f(bf16_t u) {
    return __uint_as_float(((unsigned int)u) << 16);
}
__device__ __forceinline__ bf16_t f2b(float f) {
    unsigned int x = __float_as_uint(f);
    unsigned int r = x + 0x7fffu + ((x >> 16) & 1u);
    return (bf16_t)(r >> 16);
}
__device__ __forceinline__ float ldf(const void* p, int i, int isf) {
    return isf ? ((const float*)p)[i] : b2f(((const bf16_t*)p)[i]);
}

__device__ __forceinline__ void stg16(const bf16_t* g, bf16_t* l) {
#ifdef HAS_GLL
    __builtin_amdgcn_global_load_lds(
        (const __attribute__((address_space(1))) unsigned int*)g,
        (__attribute__((address_space(3))) unsigned int*)l,
        16, 0, 0);
#else
    *(uint4*)l = *(const uint4*)g;
#endif
}

// ---- params block offsets (floats) ----
#define OFF_S0T0 0
#define OFF_W1   16
#define OFF_S1   592
#define OFF_H1   656
#define OFF_S2   720
#define OFF_H2   784
#define OFF_S3   848
#define OFF_H3   912
#define OFF_S4   976
#define OFF_H4   1040
#define OFF_SC5  1104
#define OFF_H5   1112
#define OFF_SC6  1624
#define OFF_H6   1632
#define OFF_SC7  2144
#define OFF_H7   2152
#define OFF_W8   2280
#define OFF_B8   3304
#define OFF_FLAG 4032

// ---------------------------------------------------------------------------
__global__ void detect_kernel(const void* xraw, float* prm)
{
    if (threadIdx.x == 0 && blockIdx.x == 0) {
        const unsigned int* w = (const unsigned int*)xraw;
        int good = 0;
        for (int i = 0; i < 64; i++) {
            float f = __uint_as_float(w[i] << 16);
            float a = fabsf(f);
            if (a >= 0.0009765625f && a <= 16.0f) good++;
        }
        prm[OFF_FLAG] = (good >= 32) ? 0.0f : 1.0f;  // many good => bf16
    }
}

__global__ __launch_bounds__(256) void cvtb_kernel(
    const void* __restrict__ src, bf16_t* __restrict__ dst, int n,
    const float* __restrict__ prm)
{
    const int isf = prm[OFF_FLAG] > 0.5f;
    int i = blockIdx.x * 256 + threadIdx.x;
    if (i < n) dst[i] = isf ? f2b(((const float*)src)[i]) : ((const bf16_t*)src)[i];
}

// w2 [oc][ic][tap] -> w2p [oc][tap*64+ic]
__global__ __launch_bounds__(256) void pw2_kernel(
    const void* __restrict__ src, bf16_t* __restrict__ dst,
    const float* __restrict__ prm)
{
    const int isf = prm[OFF_FLAG] > 0.5f;
    int i = blockIdx.x * 256 + threadIdx.x;
    if (i >= 36864) return;
    int oc = i / 576, r = i - oc * 576;
    int tap = r >> 6, ic = r & 63;
    dst[i] = f2b(ldf(src, oc * 576 + ic * 9 + tap, isf));
}

// w3/w4 [oc][ic][p] -> [p][oc*64+ic]
__global__ __launch_bounds__(256) void pw34_kernel(
    const void* __restrict__ src, bf16_t* __restrict__ dst,
    const float* __restrict__ prm)
{
    const int isf = prm[OFF_FLAG] > 0.5f;
    int i = blockIdx.x * 256 + threadIdx.x;
    if (i >= 524288) return;
    int p = i >> 12, r = i & 4095;
    int oc = r >> 6, ic = r & 63;
    dst[i] = f2b(ldf(src, oc * 8192 + ic * 128 + p, isf));
}

// w5 [n][c*128+p] -> w5p [n][p*64+c]
__global__ __launch_bounds__(256) void pw5_kernel(
    const void* __restrict__ src, bf16_t* __restrict__ dst,
    const float* __restrict__ prm)
{
    const int isf = prm[OFF_FLAG] > 0.5f;
    int i = blockIdx.x * 256 + threadIdx.x;
    if (i >= 4194304) return;
    int nr = i >> 13, r = i & 8191;
    int p = r >> 6, c = r & 63;
    dst[i] = f2b(ldf(src, nr * 8192 + c * 128 + p, isf));
}

__global__ __launch_bounds__(256) void fold_params_kernel(
    const void* bn0p, const void* w1, const void* b1, const void* bn1p,
    const void* b2c, const void* bn2p, const void* bn3p, const void* bn4p,
    const void* b5, const void* bn5p, const void* b6, const void* bn6p,
    const void* b7, const void* bn7p, const void* w8, const void* b8,
    float* prm)
{
    const int isf = prm[OFF_FLAG] > 0.5f;
    const int t = threadIdx.x;

    if (t == 0) {
        float g = ldf(bn0p, 0, isf), be = ldf(bn0p, 1, isf);
        float m = ldf(bn0p, 2, isf), v = ldf(bn0p, 3, isf);
        float s = g * rsqrtf(v + 1e-5f);
        prm[OFF_S0T0] = s; prm[OFF_S0T0 + 1] = be - m * s;
    }
    for (int i = t; i < 576; i += 256) prm[OFF_W1 + i] = ldf(w1, i, isf);

    if (t < 64) {
        {
            float g = ldf(bn1p, t, isf), be = ldf(bn1p, 64 + t, isf);
            float m = ldf(bn1p, 128 + t, isf), v = ldf(bn1p, 192 + t, isf);
            float s = g * rsqrtf(v + 1e-5f);
            prm[OFF_S1 + t] = s;
            prm[OFF_H1 + t] = s * ldf(b1, t, isf) + (be - m * s);
        }
        {
            float g = ldf(bn2p, t, isf), be = ldf(bn2p, 64 + t, isf);
            float m = ldf(bn2p, 128 + t, isf), v = ldf(bn2p, 192 + t, isf);
            float s = g * rsqrtf(v + 1e-5f);
            prm[OFF_S2 + t] = s;
            prm[OFF_H2 + t] = s * ldf(b2c, t, isf) + (be - m * s);
        }
        {
            float g = ldf(bn3p, t, isf), be = ldf(bn3p, 64 + t, isf);
            float m = ldf(bn3p, 128 + t, isf), v = ldf(bn3p, 192 + t, isf);
            float s = g * rsqrtf(v + 1e-5f);
            prm[OFF_S3 + t] = s;
            prm[OFF_H3 + t] = be - m * s;
        }
        {
            float g = ldf(bn4p, t, isf), be = ldf(bn4p, 64 + t, isf);
            float m = ldf(bn4p, 128 + t, isf), v = ldf(bn4p, 192 + t, isf);
            float s = g * rsqrtf(v + 1e-5f);
            prm[OFF_S4 + t] = s;
            prm[OFF_H4 + t] = be - m * s;
        }
    }
    {
        float g = ldf(bn5p, 0, isf), be = ldf(bn5p, 1, isf);
        float m = ldf(bn5p, 2, isf), v = ldf(bn5p, 3, isf);
        float s = g * rsqrtf(v + 1e-5f);
        if (t == 0) prm[OFF_SC5] = s;
        for (int i = t; i < 512; i += 256)
            prm[OFF_H5 + i] = s * ldf(b5, i, isf) + (be - m * s);
    }
    {
        float g = ldf(bn6p, 0, isf), be = ldf(bn6p, 1, isf);
        float m = ldf(bn6p, 2, isf), v = ldf(bn6p, 3, isf);
        float s = g * rsqrtf(v + 1e-5f);
        if (t == 0) prm[OFF_SC6] = s;
        for (int i = t; i < 512; i += 256)
            prm[OFF_H6 + i] = s * ldf(b6, i, isf) + (be - m * s);
    }
    {
        float g = ldf(bn7p, 0, isf), be = ldf(bn7p, 1, isf);
        float m = ldf(bn7p, 2, isf), v = ldf(bn7p, 3, isf);
        float s = g * rsqrtf(v + 1e-5f);
        if (t == 0) prm[OFF_SC7] = s;
        if (t < 128) prm[OFF_H7 + t] = s * ldf(b7, t, isf) + (be - m * s);
    }
    for (int i = t; i < 1024; i += 256) prm[OFF_W8 + i] = ldf(w8, i, isf);
    if (t < 8) prm[OFF_B8 + t] = ldf(b8, t, isf);
}

// ---------------------------------------------------------------------------
// conv1: transpose+bn0 -> conv1+bn1+relu.  One block per sample, reads raw x.
// Output PIXEL-MAJOR: c1[p][b][ic], bf16.
// ---------------------------------------------------------------------------
__global__ __launch_bounds__(256) void conv1_kernel(
    const void* __restrict__ x, const float* __restrict__ prm,
    bf16_t* __restrict__ c1, int Bc, int c0)
{
    __shared__ float xn[180];
    __shared__ float w1s[576];

    const int t = threadIdx.x;
    const int b = blockIdx.x;
    const int isf = prm[OFF_FLAG] > 0.5f;
    const float s0 = prm[OFF_S0T0], t0 = prm[OFF_S0T0 + 1];

    for (int i = t; i < 576; i += 256) w1s[i] = prm[OFF_W1 + i];
    if (t < 180) {
        int row = t / 18, col = t - row * 18;
        float v = 0.f;
        if (row >= 1 && row <= 8 && col >= 1 && col <= 16)
            v = s0 * ldf(x, (c0 + b) * 128 + (col - 1) * 8 + (row - 1), isf) + t0;
        xn[t] = v;
    }
    __syncthreads();

    const int pg  = t & 31;
    const int oc0 = (t >> 5) * 8;

    float s1[8], h1[8];
    #pragma unroll
    for (int j = 0; j < 8; j++) {
        s1[j] = prm[OFF_S1 + oc0 + j];
        h1[j] = prm[OFF_H1 + oc0 + j];
    }
    #pragma unroll
    for (int m = 0; m < 4; m++) {
        int p = pg + 32 * m;
        int h = p >> 4, w = p & 15;
        float r[9];
        #pragma unroll
        for (int dh = 0; dh < 3; dh++)
            #pragma unroll
            for (int dw = 0; dw < 3; dw++)
                r[dh * 3 + dw] = xn[(h + dh) * 18 + (w + dw)];
        u16x8 o;
        #pragma unroll
        for (int j = 0; j < 8; j++) {
            float acc = 0.f;
            #pragma unroll
            for (int k = 0; k < 9; k++) acc += r[k] * w1s[(oc0 + j) * 9 + k];
            o[j] = f2b(fmaxf(s1[j] * acc + h1[j], 0.f));
        }
        *(u16x8*)(c1 + (size_t)p * Bc * 64 + (size_t)b * 64 + oc0) = o;
    }
}

// ---------------------------------------------------------------------------
// Fused PAIR MFMA: conv2 + bn2relu -> lc3 + bn3relu -> lc4 + bn4relu for TWO
// adjacent pixels (h,w) (h,w+1) per block.  Grid (Bc/256, 64).
// conv2 weights are pixel-independent, so each staged activation plane
// (union of the two pixels' 3x3 neighborhoods: <=12 planes vs 2x9) feeds both
// pixels' MFMA with SHARED A-fragments -> staging bytes -33%, steps 36->24.
// XOR-swizzled chunk layout (chunk = row*4 + (g ^ ((row>>1)&3))): coalesced
// global_load_lds + 2-way (free) b128 fragment reads.  1-deep dbuf.
// LDS (shorts): As dbuf 2x8192 @0; Bs dbuf 2x(2 tap-tiles x 2048) @16384.
// After conv2: smC [0,18432) stride 72 (alias), lc wt stage [18432,20480).
// Total 24576 shorts = 48 KiB.
// ---------------------------------------------------------------------------
__global__ __launch_bounds__(256) void fused_pair_kernel(
    const bf16_t* __restrict__ c1, const bf16_t* __restrict__ w2p,
    const bf16_t* __restrict__ w3p, const bf16_t* __restrict__ w4p,
    const float* __restrict__ prm, bf16_t* __restrict__ bufA, int Bc)
{
    __shared__ bf16_t sm[24576];       // 48 KiB
    __shared__ int planeOff[12];       // c1 element offset of plane
    __shared__ int planeT0[12];        // tap index for pixel0 (-1 = none)
    __shared__ int planeT1[12];        // tap index for pixel1 (-1 = none)
    __shared__ int planeN;

    const int t    = threadIdx.x;
    const int lane = t & 63;
    const int wv   = t >> 6;
    const int m0   = blockIdx.x * 256;
    const int py   = blockIdx.y;
    const int h    = py >> 3, w0 = (py & 7) * 2;
    const int p0   = h * 16 + w0;

    const int fr = lane & 15;
    const int fg = lane >> 4;
    const int swz4 = (fr >> 1) & 3;
    const int orow = fg * 4;
    const int ocol = fr;

    if (t == 0) {
        int n = 0;
        for (int r = h - 1; r <= h + 1; r++) {
            if (r < 0 || r >= 8) continue;
            for (int c = w0 - 1; c <= w0 + 2; c++) {
                if (c < 0 || c >= 16) continue;
                planeOff[n] = (r * 16 + c) * Bc * 64;
                int d0 = c - w0;   // -1..2
                planeT0[n] = (d0 >= -1 && d0 <= 1) ? ((r - h + 1) * 3 + d0 + 1) : -1;
                int d1 = d0 - 1;
                planeT1[n] = (d1 >= -1 && d1 <= 1) ? ((r - h + 1) * 3 + d1 + 1) : -1;
                n++;
            }
        }
        planeN = n;
    }
    __syncthreads();
    const int S = planeN * 2;

    // staging coords (chunk index = threadIdx (+256u))
    const int rB = t >> 2;                    // B row (oc) for chunk t
    const int gS = (t & 3) ^ ((t >> 3) & 3);  // swizzled k-group for chunk t

    f32x4 acc0[4][4], acc1[4][4];
    #pragma unroll
    for (int i = 0; i < 4; i++)
        #pragma unroll
        for (int j = 0; j < 4; j++) {
            acc0[i][j] = (f32x4){0.f, 0.f, 0.f, 0.f};
            acc1[i][j] = (f32x4){0.f, 0.f, 0.f, 0.f};
        }

    // ---------------- conv2: dbuf pipeline over S 32-k plane-steps ----------------
    {   // prologue: stage step 0 into buf 0
        const bf16_t* ab = c1 + (size_t)planeOff[0] + (size_t)m0 * 64;
        #pragma unroll
        for (int u = 0; u < 4; u++) {
            const int c = t + 256 * u;
            const int row = c >> 2;
            const int g = (c & 3) ^ ((c >> 3) & 3);
            stg16(ab + row * 64 + g * 8, sm + c * 8);
        }
        const int tt0 = planeT0[0] >= 0 ? planeT0[0] : 0;
        const int tt1 = planeT1[0] >= 0 ? planeT1[0] : 0;
        stg16(w2p + rB * 576 + tt0 * 64 + gS * 8, sm + 16384 + t * 8);
        stg16(w2p + rB * 576 + tt1 * 64 + gS * 8, sm + 16384 + 2048 + t * 8);
    }
    for (int s = 0; s < S; s++) {
        const int cur = s & 1;
        __syncthreads();
        if (s + 1 < S) {
            const int nb = cur ^ 1;
            const int s1 = s + 1;
            const int pl = s1 >> 1, ic0 = (s1 & 1) * 32;
            const bf16_t* ab = c1 + (size_t)planeOff[pl] + (size_t)m0 * 64 + ic0;
            #pragma unroll
            for (int u = 0; u < 4; u++) {
                const int c = t + 256 * u;
                const int row = c >> 2;
                const int g = (c & 3) ^ ((c >> 3) & 3);
                stg16(ab + row * 64 + g * 8, sm + nb * 8192 + c * 8);
            }
            const int tt0 = planeT0[pl] >= 0 ? planeT0[pl] : 0;
            const int tt1 = planeT1[pl] >= 0 ? planeT1[pl] : 0;
            stg16(w2p + rB * 576 + tt0 * 64 + ic0 + gS * 8,
                  sm + 16384 + nb * 4096 + t * 8);
            stg16(w2p + rB * 576 + tt1 * 64 + ic0 + gS * 8,
                  sm + 16384 + nb * 4096 + 2048 + t * 8);
        }
        const bf16_t* Ab = sm + cur * 8192;
        const bf16_t* Bb = sm + 16384 + cur * 4096;
        const int pl = s >> 1;

        bf16x8 af[4];
        #pragma unroll
        for (int i = 0; i < 4; i++)
            af[i] = *(const bf16x8*)(Ab + ((wv * 64 + i * 16 + fr) * 4 + (fg ^ swz4)) * 8);

        if (planeT0[pl] >= 0) {
            bf16x8 bf[4];
            #pragma unroll
            for (int j = 0; j < 4; j++)
                bf[j] = *(const bf16x8*)(Bb + ((j * 16 + fr) * 4 + (fg ^ swz4)) * 8);
            #pragma unroll
            for (int i = 0; i < 4; i++)
                #pragma unroll
                for (int j = 0; j < 4; j++)
                    acc0[i][j] = __builtin_amdgcn_mfma_f32_16x16x32_bf16(
                        af[i], bf[j], acc0[i][j], 0, 0, 0);
        }
        if (planeT1[pl] >= 0) {
            bf16x8 bf[4];
            #pragma unroll
            for (int j = 0; j < 4; j++)
                bf[j] = *(const bf16x8*)(Bb + 2048 + ((j * 16 + fr) * 4 + (fg ^ swz4)) * 8);
            #pragma unroll
            for (int i = 0; i < 4; i++)
                #pragma unroll
                for (int j = 0; j < 4; j++)
                    acc1[i][j] = __builtin_amdgcn_mfma_f32_16x16x32_bf16(
                        af[i], bf[j], acc1[i][j], 0, 0, 0);
        }
    }
    __syncthreads();   // staging reads done; smC may overwrite

    // ---------------- per-pixel: epilogue -> smC -> lc3 -> lc4 -> bufA ----------------
    for (int px = 0; px < 2; px++) {
        const int p = p0 + px;

        // conv2 epilogue (acc of this pixel) -> smC [row][oc] stride 72
        #pragma unroll
        for (int j = 0; j < 4; j++) {
            const int oc = j * 16 + ocol;
            const float s = prm[OFF_S2 + oc], hh2 = prm[OFF_H2 + oc];
            #pragma unroll
            for (int i = 0; i < 4; i++) {
                const int rb = wv * 64 + i * 16 + orow;
                #pragma unroll
                for (int r = 0; r < 4; r++) {
                    float v = px ? acc1[i][j][r] : acc0[i][j][r];
                    sm[(rb + r) * 72 + oc] = f2b(fmaxf(s * v + hh2, 0.f));
                }
            }
        }
        __syncthreads();

        // lc3 (K=64): weights staged into [18432,20480)
        f32x4 la[4][4];
        #pragma unroll
        for (int i = 0; i < 4; i++)
            #pragma unroll
            for (int j = 0; j < 4; j++)
                la[i][j] = (f32x4){0.f, 0.f, 0.f, 0.f};

        for (int ks = 0; ks < 2; ks++) {
            stg16(w3p + (size_t)p * 4096 + rB * 64 + ks * 32 + gS * 8, sm + 18432 + t * 8);
            __syncthreads();
            bf16x8 af2[4], bf[4];
            #pragma unroll
            for (int i = 0; i < 4; i++)
                af2[i] = *(const bf16x8*)(sm + (wv * 64 + i * 16 + fr) * 72 + ks * 32 + fg * 8);
            #pragma unroll
            for (int j = 0; j < 4; j++)
                bf[j] = *(const bf16x8*)(sm + 18432 + ((j * 16 + fr) * 4 + (fg ^ swz4)) * 8);
            #pragma unroll
            for (int i = 0; i < 4; i++)
                #pragma unroll
                for (int j = 0; j < 4; j++)
                    la[i][j] = __builtin_amdgcn_mfma_f32_16x16x32_bf16(
                        af2[i], bf[j], la[i][j], 0, 0, 0);
            __syncthreads();
        }

        #pragma unroll
        for (int j = 0; j < 4; j++) {
            const int oc = j * 16 + ocol;
            const float s = prm[OFF_S3 + oc], hh3 = prm[OFF_H3 + oc];
            #pragma unroll
            for (int i = 0; i < 4; i++) {
                const int rb = wv * 64 + i * 16 + orow;
                #pragma unroll
                for (int r = 0; r < 4; r++)
                    sm[(rb + r) * 72 + oc] = f2b(fmaxf(s * la[i][j][r] + hh3, 0.f));
            }
        }
        __syncthreads();

        // lc4 (K=64)
        #pragma unroll
        for (int i = 0; i < 4; i++)
            #pragma unroll
            for (int j = 0; j < 4; j++)
                la[i][j] = (f32x4){0.f, 0.f, 0.f, 0.f};

        for (int ks = 0; ks < 2; ks++) {
            stg16(w4p + (size_t)p * 4096 + rB * 64 + ks * 32 + gS * 8, sm + 18432 + t * 8);
            __syncthreads();
            bf16x8 af2[4], bf[4];
            #pragma unroll
            for (int i = 0; i < 4; i++)
                af2[i] = *(const bf16x8*)(sm + (wv * 64 + i * 16 + fr) * 72 + ks * 32 + fg * 8);
            #pragma unroll
            for (int j = 0; j < 4; j++)
                bf[j] = *(const bf16x8*)(sm + 18432 + ((j * 16 + fr) * 4 + (fg ^ swz4)) * 8);
            #pragma unroll
            for (int i = 0; i < 4; i++)
                #pragma unroll
                for (int j = 0; j < 4; j++)
                    la[i][j] = __builtin_amdgcn_mfma_f32_16x16x32_bf16(
                        af2[i], bf[j], la[i][j], 0, 0, 0);
            __syncthreads();
        }

        #pragma unroll
        for (int j = 0; j < 4; j++) {
            const int oc = j * 16 + ocol;
            const float s = prm[OFF_S4 + oc], hh4 = prm[OFF_H4 + oc];
            #pragma unroll
            for (int i = 0; i < 4; i++) {
                const int rb = wv * 64 + i * 16 + orow;
                #pragma unroll
                for (int r = 0; r < 4; r++)
                    sm[(rb + r) * 72 + oc] = f2b(fmaxf(s * la[i][j][r] + hh4, 0.f));
            }
        }
        __syncthreads();

        const int wrow = t >> 3, wc0 = (t & 7) * 8;
        #pragma unroll
        for (int pass = 0; pass < 8; pass++) {
            const int row = wrow + pass * 32;
            *(uint4*)(bufA + (size_t)(m0 + row) * 8192 + p * 64 + wc0) =
                *(const uint4*)(sm + row * 72 + wc0);
        }
        __syncthreads();   // bufA reads of smC done before next pixel overwrites
    }
}

// ---------------------------------------------------------------------------
// MFMA GEMM: out[M][N] = relu(s*(A.W^T)+shift), bf16.
// BM=128, BN=64, BK=64.  4 waves 2x2, wave tile 64x32, 16 MFMA per barrier.
// XOR-swizzled chunks: chunk = row*8 + (g ^ (row&7)) -> coalesced gll staging
// + 2-way (free) b128 fragment reads.  1-deep dbuf, 1 barrier per k-step.
// LDS (shorts): As dbuf 2x8192 @0; Bs dbuf 2x4096 @16384.  48 KiB.
// ---------------------------------------------------------------------------
__global__ __launch_bounds__(256) void gemm_mfma(
    const bf16_t* __restrict__ A, const bf16_t* __restrict__ W,
    const float* __restrict__ prm, int sc_off, int sh_off,
    bf16_t* __restrict__ out, int K, int N)
{
    __shared__ bf16_t sm[24576];
    const int t    = threadIdx.x;
    const int lane = t & 63;
    const int wv   = t >> 6;
    const int wr   = wv >> 1, wc = wv & 1;
    const int m0   = blockIdx.x * 128, n0 = blockIdx.y * 64;

    const int fr = lane & 15;
    const int fg = lane >> 4;
    const int swz8 = fr & 7;

    // staging: A 1024 chunks (4/thread), B 512 chunks (2/thread)
    const bf16_t* srcA[4]; bf16_t* dstA[4];
    #pragma unroll
    for (int u = 0; u < 4; u++) {
        const int c = t + 256 * u;
        const int row = c >> 3;
        const int g = (c & 7) ^ (row & 7);
        srcA[u] = A + (size_t)(m0 + row) * K + g * 8;
        dstA[u] = sm + c * 8;
    }
    const bf16_t* srcB[2]; bf16_t* dstB[2];
    #pragma unroll
    for (int u = 0; u < 2; u++) {
        const int c = t + 256 * u;
        const int row = c >> 3;
        const int g = (c & 7) ^ (row & 7);
        srcB[u] = W + (size_t)(n0 + row) * K + g * 8;
        dstB[u] = sm + 16384 + c * 8;
    }

    f32x4 acc[4][2];
    #pragma unroll
    for (int i = 0; i < 4; i++)
        #pragma unroll
        for (int j = 0; j < 2; j++)
            acc[i][j] = (f32x4){0.f, 0.f, 0.f, 0.f};

    const int KS = K >> 6;

    // prologue into buf 0
    #pragma unroll
    for (int u = 0; u < 4; u++) stg16(srcA[u], dstA[u]);
    #pragma unroll
    for (int u = 0; u < 2; u++) stg16(srcB[u], dstB[u]);

    for (int ks = 0; ks < KS; ks++) {
        const int cur = ks & 1;
        __syncthreads();
        if (ks + 1 < KS) {
            const int nb = cur ^ 1;
            const int kk = (ks + 1) << 6;
            #pragma unroll
            for (int u = 0; u < 4; u++) stg16(srcA[u] + kk, dstA[u] + nb * 8192);
            #pragma unroll
            for (int u = 0; u < 2; u++) stg16(srcB[u] + kk, dstB[u] + nb * 4096);
        }
        const bf16_t* Ab = sm + cur * 8192;
        const bf16_t* Bb = sm + 16384 + cur * 4096;
        bf16x8 af[4][2], bf2[2][2];
        #pragma unroll
        for (int i = 0; i < 4; i++)
            #pragma unroll
            for (int hh = 0; hh < 2; hh++) {
                const int r = wr * 64 + i * 16 + fr;
                const int g = hh * 4 + fg;
                af[i][hh] = *(const bf16x8*)(Ab + (r * 8 + (g ^ swz8)) * 8);
            }
        #pragma unroll
        for (int j = 0; j < 2; j++)
            #pragma unroll
            for (int hh = 0; hh < 2; hh++) {
                const int r = wc * 32 + j * 16 + fr;
                const int g = hh * 4 + fg;
                bf2[j][hh] = *(const bf16x8*)(Bb + (r * 8 + (g ^ swz8)) * 8);
            }
        #pragma unroll
        for (int hh = 0; hh < 2; hh++)
            #pragma unroll
            for (int i = 0; i < 4; i++)
                #pragma unroll
                for (int j = 0; j < 2; j++)
                    acc[i][j] = __builtin_amdgcn_mfma_f32_16x16x32_bf16(
                        af[i][hh], bf2[j][hh], acc[i][j], 0, 0, 0);
    }

    const float s    = prm[sc_off];
    const int   orow = fg * 4;
    const int   ocol = fr;
    #pragma unroll
    for (int j = 0; j < 2; j++) {
        const int n  = n0 + wc * 32 + j * 16 + ocol;
        const float sh = prm[sh_off + n];
        #pragma unroll
        for (int i = 0; i < 4; i++) {
            const int mb = m0 + wr * 64 + i * 16 + orow;
            #pragma unroll
            for (int r = 0; r < 4; r++) {
                float v = fmaxf(s * acc[i][j][r] + sh, 0.f);
                out[(size_t)(mb + r) * N + n] = f2b(v);
            }
        }
    }
}

// ---------------------------------------------------------------------------
// fc8: out[b][n] = h[b][:] . w8[n][:] + b8[n]   (N=8, K=128), h is bf16
// ---------------------------------------------------------------------------
__global__ __launch_bounds__(256) void fc8_kernel(
    const bf16_t* __restrict__ h, const float* __restrict__ prm,
    void* __restrict__ out, int c0)
{
    __shared__ float wsm[8 * 129];
    const int t = threadIdx.x;
    for (int i = t; i < 1024; i += 256) {
        int n = i >> 7, k = i & 127;
        wsm[n * 129 + k] = prm[OFF_W8 + i];
    }
    __syncthreads();
    const int isf = prm[OFF_FLAG] > 0.5f;
    const int bl = t >> 3, n = t & 7;
    const int b = c0 + blockIdx.x * 32 + bl;
    const bf16_t* hb = h + (size_t)(blockIdx.x * 32 + bl) * 128;
    float acc = prm[OFF_B8 + n];
    for (int k = 0; k < 128; k++) acc += b2f(hb[k]) * wsm[n * 129 + k];
    if (isf) ((float*)out)[(size_t)b * 8 + n] = acc;
    else     ((bf16_t*)out)[(size_t)b * 8 + n] = f2b(acc);
}

// ---------------------------------------------------------------------------
extern "C" void kernel_launch(void* const* d_in, const int* in_sizes, int n_in,
                              void* d_out, int out_size, void* d_ws, size_t ws_size,
                              hipStream_t stream)
{
    const void* x    = d_in[0];
    const void* bn0p = d_in[1];
    const void* w1   = d_in[2];
    const void* b1   = d_in[3];
    const void* bn1p = d_in[4];
    const void* w2   = d_in[5];
    const void* b2c  = d_in[6];
    const void* bn2p = d_in[7];
    const void* w3   = d_in[8];
    const void* bn3p = d_in[9];
    const void* w4   = d_in[10];
    const void* bn4p = d_in[11];
    const void* w5   = d_in[12];
    const void* b5   = d_in[13];
    const void* bn5p = d_in[14];
    const void* w6   = d_in[15];
    const void* b6   = d_in[16];
    const void* bn6p = d_in[17];
    const void* w7   = d_in[18];
    const void* b7   = d_in[19];
    const void* bn7p = d_in[20];
    const void* w8   = d_in[21];
    const void* b8   = d_in[22];

    char* base = (char*)d_ws;
    float*  prm = (float*)(base + 0);            //    16384 B
    bf16_t* w2p = (bf16_t*)(base + 16384);       //    73728 B
    bf16_t* w3p = (bf16_t*)(base + 90112);       //  1048576 B
    bf16_t* w4p = (bf16_t*)(base + 1138688);     //  1048576 B
    bf16_t* w5p = (bf16_t*)(base + 2187264);     //  8388608 B
    bf16_t* w6b = (bf16_t*)(base + 10575872);    //   524288 B
    bf16_t* w7b = (bf16_t*)(base + 11100160);    //   131072 B
    char*   acts = base + 11231232;

    const int B = 8192;
    const size_t FIXED = 11231232ull;

    detect_kernel<<<1, 64, 0, stream>>>(x, prm);
    fold_params_kernel<<<1, 256, 0, stream>>>(
        bn0p, w1, b1, bn1p, b2c, bn2p, bn3p, bn4p,
        b5, bn5p, b6, bn6p, b7, bn7p, w8, b8, prm);

    pw2_kernel<<<(36864 + 255) / 256, 256, 0, stream>>>(w2, w2p, prm);
    pw34_kernel<<<(524288 + 255) / 256, 256, 0, stream>>>(w3, w3p, prm);
    pw34_kernel<<<(524288 + 255) / 256, 256, 0, stream>>>(w4, w4p, prm);
    pw5_kernel<<<(4194304 + 255) / 256, 256, 0, stream>>>(w5, w5p, prm);
    cvtb_kernel<<<(262144 + 255) / 256, 256, 0, stream>>>(w6, w6b, 262144, prm);
    cvtb_kernel<<<(65536 + 255) / 256, 256, 0, stream>>>(w7, w7b, 65536, prm);

    const int Bf = 4096;
    const size_t FULL_NEED = FIXED + (size_t)Bf * 16384ull + (size_t)B * 18688ull;

    if (ws_size >= FULL_NEED) {
        bf16_t* c1   = (bf16_t*)acts;                    // [128][Bf][64]
        bf16_t* bufA = c1 + (size_t)Bf * 8192;           // [B][8192]
        bf16_t* bufC = bufA + (size_t)B * 8192;          // [B][512]
        bf16_t* bufD = bufC + (size_t)B * 512;           // [B][512]
        bf16_t* bufE = bufD + (size_t)B * 512;           // [B][128]

        for (int c0 = 0; c0 < B; c0 += Bf) {
            conv1_kernel<<<Bf, 256, 0, stream>>>(x, prm, c1, Bf, c0);
            fused_pair_kernel<<<dim3(Bf / 256, 64), 256, 0, stream>>>(
                c1, w2p, w3p, w4p, prm, bufA + (size_t)c0 * 8192, Bf);
        }
        gemm_mfma<<<dim3(B / 128, 8), 256, 0, stream>>>(
            bufA, w5p, prm, OFF_SC5, OFF_H5, bufC, 8192, 512);
        gemm_mfma<<<dim3(B / 128, 8), 256, 0, stream>>>(
            bufC, w6b, prm, OFF_SC6, OFF_H6, bufD, 512, 512);
        gemm_mfma<<<dim3(B / 128, 2), 256, 0, stream>>>(
            bufD, w7b, prm, OFF_SC7, OFF_H7, bufE, 512, 128);
        fc8_kernel<<<B / 32, 256, 0, stream>>>(bufE, prm, d_out, 0);
    } else {
        size_t avail = (ws_size > FIXED) ? (ws_size - FIXED) : 0;
        int Bc = 8192;
        while (Bc > 256 && (size_t)Bc * 35072ull > avail) Bc >>= 1;

        bf16_t* c1   = (bf16_t*)acts;
        bf16_t* bufA = c1 + (size_t)Bc * 8192;
        bf16_t* bufC = bufA + (size_t)Bc * 8192;
        bf16_t* bufD = bufC + (size_t)Bc * 512;
        bf16_t* bufE = bufD + (size_t)Bc * 512;

        for (int c0 = 0; c0 < B; c0 += Bc) {
            conv1_kernel<<<Bc, 256, 0, stream>>>(x, prm, c1, Bc, c0);
            fused_pair_kernel<<<dim3(Bc / 256, 64), 256, 0, stream>>>(
                c1, w2p, w3p, w4p, prm, bufA, Bc);
            gemm_mfma<<<dim3(Bc / 128, 8), 256, 0, stream>>>(
                bufA, w5p, prm, OFF_SC5, OFF_H5, bufC, 8192, 512);
            gemm_mfma<<<dim3(Bc / 128, 8), 256, 0, stream>>>(
                bufC, w6b, prm, OFF_SC6, OFF_H6, bufD, 512, 512);
            gemm_mfma<<<dim3(Bc / 128, 2), 256, 0, stream>>>(
                bufD, w7b, prm, OFF_SC7, OFF_H7, bufE, 512, 128);
            fc8_kernel<<<Bc / 32, 256, 0, stream>>>(bufE, prm, d_out, c0);
        }
    }
}

// Round 9
// 444.400 us; speedup vs baseline: 1.3504x; 1.3504x over previous
//
#include <hip/hip_runtime.h>

typedef unsigned short bf16_t;
typedef __attribute__((ext_vector_type(8))) short bf16x8;
typedef __attribute__((ext_vector_type(8))) unsigned short u16x8;
typedef __attribute__((ext_vector_type(4))) float f32x4;

#if defined(__has_builtin)
#if __has_builtin(__builtin_amdgcn_global_load_lds)
#define HAS_GLL 1
#endif
#endif

__device__ __forceinline__ float b2f(bf16_t u) {
    return __uint_as_float(((unsigned int)u) << 16);
}
__device__ __forceinline__ bf16_t f2b(float f) {
    unsigned int x = __float_as_uint(f);
    unsigned int r = x + 0x7fffu + ((x >> 16) & 1u);
    return (bf16_t)(r >> 16);
}
__device__ __forceinline__ float ldf(const void* p, int i, int isf) {
    return isf ? ((const float*)p)[i] : b2f(((const bf16_t*)p)[i]);
}

__device__ __forceinline__ void stg16(const bf16_t* g, bf16_t* l) {
#ifdef HAS_GLL
    __builtin_amdgcn_global_load_lds(
        (const __attribute__((address_space(1))) unsigned int*)g,
        (__attribute__((address_space(3))) unsigned int*)l,
        16, 0, 0);
#else
    *(uint4*)l = *(const uint4*)g;
#endif
}

// ---- params block offsets (floats) ----
#define OFF_S0T0 0
#define OFF_W1   16
#define OFF_S1   592
#define OFF_H1   656
#define OFF_S2   720
#define OFF_H2   784
#define OFF_S3   848
#define OFF_H3   912
#define OFF_S4   976
#define OFF_H4   1040
#define OFF_SC5  1104
#define OFF_H5   1112
#define OFF_SC6  1624
#define OFF_H6   1632
#define OFF_SC7  2144
#define OFF_H7   2152
#define OFF_W8   2280
#define OFF_B8   3304
#define OFF_FLAG 4032

// ---------------------------------------------------------------------------
__global__ void detect_kernel(const void* xraw, float* prm)
{
    if (threadIdx.x == 0 && blockIdx.x == 0) {
        const unsigned int* w = (const unsigned int*)xraw;
        int good = 0;
        for (int i = 0; i < 64; i++) {
            float f = __uint_as_float(w[i] << 16);
            float a = fabsf(f);
            if (a >= 0.0009765625f && a <= 16.0f) good++;
        }
        prm[OFF_FLAG] = (good >= 32) ? 0.0f : 1.0f;  // many good => bf16
    }
}

__global__ __launch_bounds__(256) void cvtb_kernel(
    const void* __restrict__ src, bf16_t* __restrict__ dst, int n,
    const float* __restrict__ prm)
{
    const int isf = prm[OFF_FLAG] > 0.5f;
    int i = blockIdx.x * 256 + threadIdx.x;
    if (i < n) dst[i] = isf ? f2b(((const float*)src)[i]) : ((const bf16_t*)src)[i];
}

// w2 [oc][ic][tap] -> w2p [oc][tap*64+ic]
__global__ __launch_bounds__(256) void pw2_kernel(
    const void* __restrict__ src, bf16_t* __restrict__ dst,
    const float* __restrict__ prm)
{
    const int isf = prm[OFF_FLAG] > 0.5f;
    int i = blockIdx.x * 256 + threadIdx.x;
    if (i >= 36864) return;
    int oc = i / 576, r = i - oc * 576;
    int tap = r >> 6, ic = r & 63;
    dst[i] = f2b(ldf(src, oc * 576 + ic * 9 + tap, isf));
}

// w3/w4 [oc][ic][p] -> [p][oc*64+ic]
__global__ __launch_bounds__(256) void pw34_kernel(
    const void* __restrict__ src, bf16_t* __restrict__ dst,
    const float* __restrict__ prm)
{
    const int isf = prm[OFF_FLAG] > 0.5f;
    int i = blockIdx.x * 256 + threadIdx.x;
    if (i >= 524288) return;
    int p = i >> 12, r = i & 4095;
    int oc = r >> 6, ic = r & 63;
    dst[i] = f2b(ldf(src, oc * 8192 + ic * 128 + p, isf));
}

// w5 [n][c*128+p] -> w5p [n][p*64+c]
__global__ __launch_bounds__(256) void pw5_kernel(
    const void* __restrict__ src, bf16_t* __restrict__ dst,
    const float* __restrict__ prm)
{
    const int isf = prm[OFF_FLAG] > 0.5f;
    int i = blockIdx.x * 256 + threadIdx.x;
    if (i >= 4194304) return;
    int nr = i >> 13, r = i & 8191;
    int p = r >> 6, c = r & 63;
    dst[i] = f2b(ldf(src, nr * 8192 + c * 128 + p, isf));
}

__global__ __launch_bounds__(256) void fold_params_kernel(
    const void* bn0p, const void* w1, const void* b1, const void* bn1p,
    const void* b2c, const void* bn2p, const void* bn3p, const void* bn4p,
    const void* b5, const void* bn5p, const void* b6, const void* bn6p,
    const void* b7, const void* bn7p, const void* w8, const void* b8,
    float* prm)
{
    const int isf = prm[OFF_FLAG] > 0.5f;
    const int t = threadIdx.x;

    if (t == 0) {
        float g = ldf(bn0p, 0, isf), be = ldf(bn0p, 1, isf);
        float m = ldf(bn0p, 2, isf), v = ldf(bn0p, 3, isf);
        float s = g * rsqrtf(v + 1e-5f);
        prm[OFF_S0T0] = s; prm[OFF_S0T0 + 1] = be - m * s;
    }
    for (int i = t; i < 576; i += 256) prm[OFF_W1 + i] = ldf(w1, i, isf);

    if (t < 64) {
        {
            float g = ldf(bn1p, t, isf), be = ldf(bn1p, 64 + t, isf);
            float m = ldf(bn1p, 128 + t, isf), v = ldf(bn1p, 192 + t, isf);
            float s = g * rsqrtf(v + 1e-5f);
            prm[OFF_S1 + t] = s;
            prm[OFF_H1 + t] = s * ldf(b1, t, isf) + (be - m * s);
        }
        {
            float g = ldf(bn2p, t, isf), be = ldf(bn2p, 64 + t, isf);
            float m = ldf(bn2p, 128 + t, isf), v = ldf(bn2p, 192 + t, isf);
            float s = g * rsqrtf(v + 1e-5f);
            prm[OFF_S2 + t] = s;
            prm[OFF_H2 + t] = s * ldf(b2c, t, isf) + (be - m * s);
        }
        {
            float g = ldf(bn3p, t, isf), be = ldf(bn3p, 64 + t, isf);
            float m = ldf(bn3p, 128 + t, isf), v = ldf(bn3p, 192 + t, isf);
            float s = g * rsqrtf(v + 1e-5f);
            prm[OFF_S3 + t] = s;
            prm[OFF_H3 + t] = be - m * s;
        }
        {
            float g = ldf(bn4p, t, isf), be = ldf(bn4p, 64 + t, isf);
            float m = ldf(bn4p, 128 + t, isf), v = ldf(bn4p, 192 + t, isf);
            float s = g * rsqrtf(v + 1e-5f);
            prm[OFF_S4 + t] = s;
            prm[OFF_H4 + t] = be - m * s;
        }
    }
    {
        float g = ldf(bn5p, 0, isf), be = ldf(bn5p, 1, isf);
        float m = ldf(bn5p, 2, isf), v = ldf(bn5p, 3, isf);
        float s = g * rsqrtf(v + 1e-5f);
        if (t == 0) prm[OFF_SC5] = s;
        for (int i = t; i < 512; i += 256)
            prm[OFF_H5 + i] = s * ldf(b5, i, isf) + (be - m * s);
    }
    {
        float g = ldf(bn6p, 0, isf), be = ldf(bn6p, 1, isf);
        float m = ldf(bn6p, 2, isf), v = ldf(bn6p, 3, isf);
        float s = g * rsqrtf(v + 1e-5f);
        if (t == 0) prm[OFF_SC6] = s;
        for (int i = t; i < 512; i += 256)
            prm[OFF_H6 + i] = s * ldf(b6, i, isf) + (be - m * s);
    }
    {
        float g = ldf(bn7p, 0, isf), be = ldf(bn7p, 1, isf);
        float m = ldf(bn7p, 2, isf), v = ldf(bn7p, 3, isf);
        float s = g * rsqrtf(v + 1e-5f);
        if (t == 0) prm[OFF_SC7] = s;
        if (t < 128) prm[OFF_H7 + t] = s * ldf(b7, t, isf) + (be - m * s);
    }
    for (int i = t; i < 1024; i += 256) prm[OFF_W8 + i] = ldf(w8, i, isf);
    if (t < 8) prm[OFF_B8 + t] = ldf(b8, t, isf);
}

// ---------------------------------------------------------------------------
// conv1: transpose+bn0 -> conv1+bn1+relu.  FOUR samples per block (w1 staged
// once, 1/4 the dispatch grid).  Output PIXEL-MAJOR: c1[p][b][ic], bf16.
// ---------------------------------------------------------------------------
__global__ __launch_bounds__(256) void conv1_kernel(
    const void* __restrict__ x, const float* __restrict__ prm,
    bf16_t* __restrict__ c1, int Bc, int c0)
{
    __shared__ float xn[180];
    __shared__ float w1s[576];

    const int t = threadIdx.x;
    const int b0 = blockIdx.x * 4;
    const int isf = prm[OFF_FLAG] > 0.5f;
    const float s0 = prm[OFF_S0T0], t0 = prm[OFF_S0T0 + 1];

    for (int i = t; i < 576; i += 256) w1s[i] = prm[OFF_W1 + i];

    const int pg  = t & 31;
    const int oc0 = (t >> 5) * 8;

    float s1[8], h1[8];
    #pragma unroll
    for (int j = 0; j < 8; j++) {
        s1[j] = prm[OFF_S1 + oc0 + j];
        h1[j] = prm[OFF_H1 + oc0 + j];
    }

    for (int s = 0; s < 4; s++) {
        const int b = b0 + s;
        __syncthreads();           // xn reads of prev sample done / w1s ready
        if (t < 180) {
            int row = t / 18, col = t - row * 18;
            float v = 0.f;
            if (row >= 1 && row <= 8 && col >= 1 && col <= 16)
                v = s0 * ldf(x, (c0 + b) * 128 + (col - 1) * 8 + (row - 1), isf) + t0;
            xn[t] = v;
        }
        __syncthreads();

        #pragma unroll
        for (int m = 0; m < 4; m++) {
            int p = pg + 32 * m;
            int h = p >> 4, w = p & 15;
            float r[9];
            #pragma unroll
            for (int dh = 0; dh < 3; dh++)
                #pragma unroll
                for (int dw = 0; dw < 3; dw++)
                    r[dh * 3 + dw] = xn[(h + dh) * 18 + (w + dw)];
            u16x8 o;
            #pragma unroll
            for (int j = 0; j < 8; j++) {
                float acc = 0.f;
                #pragma unroll
                for (int k = 0; k < 9; k++) acc += r[k] * w1s[(oc0 + j) * 9 + k];
                o[j] = f2b(fmaxf(s1[j] * acc + h1[j], 0.f));
            }
            *(u16x8*)(c1 + (size_t)p * Bc * 64 + (size_t)b * 64 + oc0) = o;
        }
    }
}

// ---------------------------------------------------------------------------
// Fused MFMA: conv2(im2col K=576) + bn2relu -> lc3(K=64) + bn3relu
//             -> lc4(K=64) + bn4relu.  Grid (Bc/256, 128 pixels).
// 18 fixed k-steps with UNIFORM validity predicates (no LDS tap tables) so
// LDS = exactly 40960 B -> 4 blocks/CU.  XOR-swizzled chunk layout
// (chunk = row*4 + (g ^ ((row>>1)&3))): coalesced global_load_lds + 2-way
// (free) b128 fragment reads.  1-deep dbuf: at step s stage s+1 (if valid),
// compute s (if valid) -- every valid step staged exactly 1 barrier earlier.
// LDS (shorts): As dbuf [0,8192)+[8192,16384); Bs dbuf [16384,18432)+
// [18432,20480); smC [0,18432) stride 72 (alias); lc weights [18432,20480).
// ---------------------------------------------------------------------------
__global__ __launch_bounds__(256) void fused_mfma_kernel(
    const bf16_t* __restrict__ c1, const bf16_t* __restrict__ w2p,
    const bf16_t* __restrict__ w3p, const bf16_t* __restrict__ w4p,
    const float* __restrict__ prm, bf16_t* __restrict__ bufA, int Bc)
{
    __shared__ bf16_t sm[20480];       // exactly 40 KiB
    const int t    = threadIdx.x;
    const int lane = t & 63;
    const int wv   = t >> 6;
    const int m0   = blockIdx.x * 256;
    const int p    = blockIdx.y;
    const int h    = p >> 4, w = p & 15;

    const int fr = lane & 15;
    const int fg = lane >> 4;
    const int swz4 = (fr >> 1) & 3;
    const int orow = fg * 4;
    const int ocol = fr;

    // staging-side swizzled coords
    const int rA = t >> 2;                        // base row for chunk t
    const int gS = (t & 3) ^ ((t >> 3) & 3);      // swizzled k-group for chunk t

    f32x4 acc[4][4];
    #pragma unroll
    for (int i = 0; i < 4; i++)
        #pragma unroll
        for (int j = 0; j < 4; j++)
            acc[i][j] = (f32x4){0.f, 0.f, 0.f, 0.f};

    // ---------------- conv2: dbuf pipeline over 18 fixed k-steps ----------------
    // step s: tap = s>>1, ic0 = (s&1)*32; valid iff neighbor pixel in-bounds.
    {   // prologue: stage step 0 (tap 0 = (-1,-1)) if valid
        if (h > 0 && w > 0) {
            const bf16_t* ab = c1 + (size_t)((h - 1) * 16 + (w - 1)) * Bc * 64
                             + (size_t)m0 * 64;
            #pragma unroll
            for (int u = 0; u < 4; u++) {
                const int c = t + 256 * u;
                const int row = c >> 2;
                const int g = (c & 3) ^ ((c >> 3) & 3);
                stg16(ab + row * 64 + g * 8, sm + c * 8);
            }
            stg16(w2p + rA * 576 + gS * 8, sm + 16384 + t * 8);
        }
    }
    for (int s = 0; s < 18; s++) {
        const int cur = s & 1;
        __syncthreads();
        if (s + 1 < 18) {
            const int s1 = s + 1;
            const int tap = s1 >> 1;
            const int dh = tap / 3 - 1, dw = tap % 3 - 1;
            const int hh = h + dh, ww = w + dw;
            if (hh >= 0 && hh < 8 && ww >= 0 && ww < 16) {   // uniform
                const int nb = cur ^ 1;
                const int ic0 = (s1 & 1) * 32;
                const bf16_t* ab = c1 + (size_t)(hh * 16 + ww) * Bc * 64
                                 + (size_t)m0 * 64 + ic0;
                #pragma unroll
                for (int u = 0; u < 4; u++) {
                    const int c = t + 256 * u;
                    const int row = c >> 2;
                    const int g = (c & 3) ^ ((c >> 3) & 3);
                    stg16(ab + row * 64 + g * 8, sm + nb * 8192 + c * 8);
                }
                stg16(w2p + rA * 576 + tap * 64 + ic0 + gS * 8,
                      sm + 16384 + nb * 2048 + t * 8);
            }
        }
        {
            const int tap = s >> 1;
            const int dh = tap / 3 - 1, dw = tap % 3 - 1;
            const int hh = h + dh, ww = w + dw;
            if (hh >= 0 && hh < 8 && ww >= 0 && ww < 16) {   // uniform
                const bf16_t* Ab = sm + cur * 8192;
                const bf16_t* Bb = sm + 16384 + cur * 2048;
                bf16x8 af[4], bf[4];
                #pragma unroll
                for (int i = 0; i < 4; i++)
                    af[i] = *(const bf16x8*)(Ab + ((wv * 64 + i * 16 + fr) * 4 + (fg ^ swz4)) * 8);
                #pragma unroll
                for (int j = 0; j < 4; j++)
                    bf[j] = *(const bf16x8*)(Bb + ((j * 16 + fr) * 4 + (fg ^ swz4)) * 8);
                #pragma unroll
                for (int i = 0; i < 4; i++)
                    #pragma unroll
                    for (int j = 0; j < 4; j++)
                        acc[i][j] = __builtin_amdgcn_mfma_f32_16x16x32_bf16(
                            af[i], bf[j], acc[i][j], 0, 0, 0);
            }
        }
    }
    __syncthreads();   // all ds_reads done before smC overwrites staging

    // conv2 epilogue -> smC [row][oc] stride 72
    #pragma unroll
    for (int j = 0; j < 4; j++) {
        const int oc = j * 16 + ocol;
        const float s = prm[OFF_S2 + oc], hh2 = prm[OFF_H2 + oc];
        #pragma unroll
        for (int i = 0; i < 4; i++) {
            const int rb = wv * 64 + i * 16 + orow;
            #pragma unroll
            for (int r = 0; r < 4; r++)
                sm[(rb + r) * 72 + oc] = f2b(fmaxf(s * acc[i][j][r] + hh2, 0.f));
        }
    }
    __syncthreads();

    // ---------------- lc3: K=64, weights staged into [18432,20480) ----------------
    #pragma unroll
    for (int i = 0; i < 4; i++)
        #pragma unroll
        for (int j = 0; j < 4; j++)
            acc[i][j] = (f32x4){0.f, 0.f, 0.f, 0.f};

    for (int ks = 0; ks < 2; ks++) {
        stg16(w3p + (size_t)p * 4096 + rA * 64 + ks * 32 + gS * 8, sm + 18432 + t * 8);
        __syncthreads();
        bf16x8 af[4], bf[4];
        #pragma unroll
        for (int i = 0; i < 4; i++)
            af[i] = *(const bf16x8*)(sm + (wv * 64 + i * 16 + fr) * 72 + ks * 32 + fg * 8);
        #pragma unroll
        for (int j = 0; j < 4; j++)
            bf[j] = *(const bf16x8*)(sm + 18432 + ((j * 16 + fr) * 4 + (fg ^ swz4)) * 8);
        #pragma unroll
        for (int i = 0; i < 4; i++)
            #pragma unroll
            for (int j = 0; j < 4; j++)
                acc[i][j] = __builtin_amdgcn_mfma_f32_16x16x32_bf16(
                    af[i], bf[j], acc[i][j], 0, 0, 0);
        __syncthreads();
    }

    #pragma unroll
    for (int j = 0; j < 4; j++) {
        const int oc = j * 16 + ocol;
        const float s = prm[OFF_S3 + oc], hh3 = prm[OFF_H3 + oc];
        #pragma unroll
        for (int i = 0; i < 4; i++) {
            const int rb = wv * 64 + i * 16 + orow;
            #pragma unroll
            for (int r = 0; r < 4; r++)
                sm[(rb + r) * 72 + oc] = f2b(fmaxf(s * acc[i][j][r] + hh3, 0.f));
        }
    }
    __syncthreads();

    // ---------------- lc4: K=64 ----------------
    #pragma unroll
    for (int i = 0; i < 4; i++)
        #pragma unroll
        for (int j = 0; j < 4; j++)
            acc[i][j] = (f32x4){0.f, 0.f, 0.f, 0.f};

    for (int ks = 0; ks < 2; ks++) {
        stg16(w4p + (size_t)p * 4096 + rA * 64 + ks * 32 + gS * 8, sm + 18432 + t * 8);
        __syncthreads();
        bf16x8 af[4], bf[4];
        #pragma unroll
        for (int i = 0; i < 4; i++)
            af[i] = *(const bf16x8*)(sm + (wv * 64 + i * 16 + fr) * 72 + ks * 32 + fg * 8);
        #pragma unroll
        for (int j = 0; j < 4; j++)
            bf[j] = *(const bf16x8*)(sm + 18432 + ((j * 16 + fr) * 4 + (fg ^ swz4)) * 8);
        #pragma unroll
        for (int i = 0; i < 4; i++)
            #pragma unroll
            for (int j = 0; j < 4; j++)
                acc[i][j] = __builtin_amdgcn_mfma_f32_16x16x32_bf16(
                    af[i], bf[j], acc[i][j], 0, 0, 0);
        __syncthreads();
    }

    #pragma unroll
    for (int j = 0; j < 4; j++) {
        const int oc = j * 16 + ocol;
        const float s = prm[OFF_S4 + oc], hh4 = prm[OFF_H4 + oc];
        #pragma unroll
        for (int i = 0; i < 4; i++) {
            const int rb = wv * 64 + i * 16 + orow;
            #pragma unroll
            for (int r = 0; r < 4; r++)
                sm[(rb + r) * 72 + oc] = f2b(fmaxf(s * acc[i][j][r] + hh4, 0.f));
        }
    }
    __syncthreads();

    const int wrow = t >> 3, wc0 = (t & 7) * 8;
    #pragma unroll
    for (int pass = 0; pass < 8; pass++) {
        const int row = wrow + pass * 32;
        *(uint4*)(bufA + (size_t)(m0 + row) * 8192 + p * 64 + wc0) =
            *(const uint4*)(sm + row * 72 + wc0);
    }
}

// ---------------------------------------------------------------------------
// MFMA GEMM: out[M][N] = relu(s*(A.W^T)+shift), bf16.
// BM=128, BN=64, BK=64.  4 waves 2x2, wave tile 64x32, 16 MFMA per barrier.
// XOR-swizzled chunks: chunk = row*8 + (g ^ (row&7)) -> coalesced gll staging
// + 2-way (free) b128 fragment reads.  1-deep dbuf, 1 barrier per k-step.
// LDS (shorts): As dbuf 2x8192 @0; Bs dbuf 2x4096 @16384.  48 KiB.
// ---------------------------------------------------------------------------
__global__ __launch_bounds__(256) void gemm_mfma(
    const bf16_t* __restrict__ A, const bf16_t* __restrict__ W,
    const float* __restrict__ prm, int sc_off, int sh_off,
    bf16_t* __restrict__ out, int K, int N)
{
    __shared__ bf16_t sm[24576];
    const int t    = threadIdx.x;
    const int lane = t & 63;
    const int wv   = t >> 6;
    const int wr   = wv >> 1, wc = wv & 1;
    const int m0   = blockIdx.x * 128, n0 = blockIdx.y * 64;

    const int fr = lane & 15;
    const int fg = lane >> 4;
    const int swz8 = fr & 7;

    const bf16_t* srcA[4]; bf16_t* dstA[4];
    #pragma unroll
    for (int u = 0; u < 4; u++) {
        const int c = t + 256 * u;
        const int row = c >> 3;
        const int g = (c & 7) ^ (row & 7);
        srcA[u] = A + (size_t)(m0 + row) * K + g * 8;
        dstA[u] = sm + c * 8;
    }
    const bf16_t* srcB[2]; bf16_t* dstB[2];
    #pragma unroll
    for (int u = 0; u < 2; u++) {
        const int c = t + 256 * u;
        const int row = c >> 3;
        const int g = (c & 7) ^ (row & 7);
        srcB[u] = W + (size_t)(n0 + row) * K + g * 8;
        dstB[u] = sm + 16384 + c * 8;
    }

    f32x4 acc[4][2];
    #pragma unroll
    for (int i = 0; i < 4; i++)
        #pragma unroll
        for (int j = 0; j < 2; j++)
            acc[i][j] = (f32x4){0.f, 0.f, 0.f, 0.f};

    const int KS = K >> 6;

    #pragma unroll
    for (int u = 0; u < 4; u++) stg16(srcA[u], dstA[u]);
    #pragma unroll
    for (int u = 0; u < 2; u++) stg16(srcB[u], dstB[u]);

    for (int ks = 0; ks < KS; ks++) {
        const int cur = ks & 1;
        __syncthreads();
        if (ks + 1 < KS) {
            const int nb = cur ^ 1;
            const int kk = (ks + 1) << 6;
            #pragma unroll
            for (int u = 0; u < 4; u++) stg16(srcA[u] + kk, dstA[u] + nb * 8192);
            #pragma unroll
            for (int u = 0; u < 2; u++) stg16(srcB[u] + kk, dstB[u] + nb * 4096);
        }
        const bf16_t* Ab = sm + cur * 8192;
        const bf16_t* Bb = sm + 16384 + cur * 4096;
        bf16x8 af[4][2], bf2[2][2];
        #pragma unroll
        for (int i = 0; i < 4; i++)
            #pragma unroll
            for (int hh = 0; hh < 2; hh++) {
                const int r = wr * 64 + i * 16 + fr;
                const int g = hh * 4 + fg;
                af[i][hh] = *(const bf16x8*)(Ab + (r * 8 + (g ^ swz8)) * 8);
            }
        #pragma unroll
        for (int j = 0; j < 2; j++)
            #pragma unroll
            for (int hh = 0; hh < 2; hh++) {
                const int r = wc * 32 + j * 16 + fr;
                const int g = hh * 4 + fg;
                bf2[j][hh] = *(const bf16x8*)(Bb + (r * 8 + (g ^ swz8)) * 8);
            }
        #pragma unroll
        for (int hh = 0; hh < 2; hh++)
            #pragma unroll
            for (int i = 0; i < 4; i++)
                #pragma unroll
                for (int j = 0; j < 2; j++)
                    acc[i][j] = __builtin_amdgcn_mfma_f32_16x16x32_bf16(
                        af[i][hh], bf2[j][hh], acc[i][j], 0, 0, 0);
    }

    const float s    = prm[sc_off];
    const int   orow = fg * 4;
    const int   ocol = fr;
    #pragma unroll
    for (int j = 0; j < 2; j++) {
        const int n  = n0 + wc * 32 + j * 16 + ocol;
        const float sh = prm[sh_off + n];
        #pragma unroll
        for (int i = 0; i < 4; i++) {
            const int mb = m0 + wr * 64 + i * 16 + orow;
            #pragma unroll
            for (int r = 0; r < 4; r++) {
                float v = fmaxf(s * acc[i][j][r] + sh, 0.f);
                out[(size_t)(mb + r) * N + n] = f2b(v);
            }
        }
    }
}

// ---------------------------------------------------------------------------
// fc8: out[b][n] = h[b][:] . w8[n][:] + b8[n]   (N=8, K=128), h is bf16
// ---------------------------------------------------------------------------
__global__ __launch_bounds__(256) void fc8_kernel(
    const bf16_t* __restrict__ h, const float* __restrict__ prm,
    void* __restrict__ out, int c0)
{
    __shared__ float wsm[8 * 129];
    const int t = threadIdx.x;
    for (int i = t; i < 1024; i += 256) {
        int n = i >> 7, k = i & 127;
        wsm[n * 129 + k] = prm[OFF_W8 + i];
    }
    __syncthreads();
    const int isf = prm[OFF_FLAG] > 0.5f;
    const int bl = t >> 3, n = t & 7;
    const int b = c0 + blockIdx.x * 32 + bl;
    const bf16_t* hb = h + (size_t)(blockIdx.x * 32 + bl) * 128;
    float acc = prm[OFF_B8 + n];
    for (int k = 0; k < 128; k++) acc += b2f(hb[k]) * wsm[n * 129 + k];
    if (isf) ((float*)out)[(size_t)b * 8 + n] = acc;
    else     ((bf16_t*)out)[(size_t)b * 8 + n] = f2b(acc);
}

// ---------------------------------------------------------------------------
extern "C" void kernel_launch(void* const* d_in, const int* in_sizes, int n_in,
                              void* d_out, int out_size, void* d_ws, size_t ws_size,
                              hipStream_t stream)
{
    const void* x    = d_in[0];
    const void* bn0p = d_in[1];
    const void* w1   = d_in[2];
    const void* b1   = d_in[3];
    const void* bn1p = d_in[4];
    const void* w2   = d_in[5];
    const void* b2c  = d_in[6];
    const void* bn2p = d_in[7];
    const void* w3   = d_in[8];
    const void* bn3p = d_in[9];
    const void* w4   = d_in[10];
    const void* bn4p = d_in[11];
    const void* w5   = d_in[12];
    const void* b5   = d_in[13];
    const void* bn5p = d_in[14];
    const void* w6   = d_in[15];
    const void* b6   = d_in[16];
    const void* bn6p = d_in[17];
    const void* w7   = d_in[18];
    const void* b7   = d_in[19];
    const void* bn7p = d_in[20];
    const void* w8   = d_in[21];
    const void* b8   = d_in[22];

    char* base = (char*)d_ws;
    float*  prm = (float*)(base + 0);            //    16384 B
    bf16_t* w2p = (bf16_t*)(base + 16384);       //    73728 B
    bf16_t* w3p = (bf16_t*)(base + 90112);       //  1048576 B
    bf16_t* w4p = (bf16_t*)(base + 1138688);     //  1048576 B
    bf16_t* w5p = (bf16_t*)(base + 2187264);     //  8388608 B
    bf16_t* w6b = (bf16_t*)(base + 10575872);    //   524288 B
    bf16_t* w7b = (bf16_t*)(base + 11100160);    //   131072 B
    char*   acts = base + 11231232;

    const int B = 8192;
    const size_t FIXED = 11231232ull;

    detect_kernel<<<1, 64, 0, stream>>>(x, prm);
    fold_params_kernel<<<1, 256, 0, stream>>>(
        bn0p, w1, b1, bn1p, b2c, bn2p, bn3p, bn4p,
        b5, bn5p, b6, bn6p, b7, bn7p, w8, b8, prm);

    pw2_kernel<<<(36864 + 255) / 256, 256, 0, stream>>>(w2, w2p, prm);
    pw34_kernel<<<(524288 + 255) / 256, 256, 0, stream>>>(w3, w3p, prm);
    pw34_kernel<<<(524288 + 255) / 256, 256, 0, stream>>>(w4, w4p, prm);
    pw5_kernel<<<(4194304 + 255) / 256, 256, 0, stream>>>(w5, w5p, prm);
    cvtb_kernel<<<(262144 + 255) / 256, 256, 0, stream>>>(w6, w6b, 262144, prm);
    cvtb_kernel<<<(65536 + 255) / 256, 256, 0, stream>>>(w7, w7b, 65536, prm);

    const int Bf = 4096;
    const size_t FULL_NEED = FIXED + (size_t)Bf * 16384ull + (size_t)B * 18688ull;

    if (ws_size >= FULL_NEED) {
        bf16_t* c1   = (bf16_t*)acts;                    // [128][Bf][64]
        bf16_t* bufA = c1 + (size_t)Bf * 8192;           // [B][8192]
        bf16_t* bufC = bufA + (size_t)B * 8192;          // [B][512]
        bf16_t* bufD = bufC + (size_t)B * 512;           // [B][512]
        bf16_t* bufE = bufD + (size_t)B * 512;           // [B][128]

        for (int c0 = 0; c0 < B; c0 += Bf) {
            conv1_kernel<<<Bf / 4, 256, 0, stream>>>(x, prm, c1, Bf, c0);
            fused_mfma_kernel<<<dim3(Bf / 256, 128), 256, 0, stream>>>(
                c1, w2p, w3p, w4p, prm, bufA + (size_t)c0 * 8192, Bf);
        }
        gemm_mfma<<<dim3(B / 128, 8), 256, 0, stream>>>(
            bufA, w5p, prm, OFF_SC5, OFF_H5, bufC, 8192, 512);
        gemm_mfma<<<dim3(B / 128, 8), 256, 0, stream>>>(
            bufC, w6b, prm, OFF_SC6, OFF_H6, bufD, 512, 512);
        gemm_mfma<<<dim3(B / 128, 2), 256, 0, stream>>>(
            bufD, w7b, prm, OFF_SC7, OFF_H7, bufE, 512, 128);
        fc8_kernel<<<B / 32, 256, 0, stream>>>(bufE, prm, d_out, 0);
    } else {
        size_t avail = (ws_size > FIXED) ? (ws_size - FIXED) : 0;
        int Bc = 8192;
        while (Bc > 256 && (size_t)Bc * 35072ull > avail) Bc >>= 1;

        bf16_t* c1   = (bf16_t*)acts;
        bf16_t* bufA = c1 + (size_t)Bc * 8192;
        bf16_t* bufC = bufA + (size_t)Bc * 8192;
        bf16_t* bufD = bufC + (size_t)Bc * 512;
        bf16_t* bufE = bufD + (size_t)Bc * 512;

        for (int c0 = 0; c0 < B; c0 += Bc) {
            conv1_kernel<<<Bc / 4, 256, 0, stream>>>(x, prm, c1, Bc, c0);
            fused_mfma_kernel<<<dim3(Bc / 256, 128), 256, 0, stream>>>(
                c1, w2p, w3p, w4p, prm, bufA, Bc);
            gemm_mfma<<<dim3(Bc / 128, 8), 256, 0, stream>>>(
                bufA, w5p, prm, OFF_SC5, OFF_H5, bufC, 8192, 512);
            gemm_mfma<<<dim3(Bc / 128, 8), 256, 0, stream>>>(
                bufC, w6b, prm, OFF_SC6, OFF_H6, bufD, 512, 512);
            gemm_mfma<<<dim3(Bc / 128, 2), 256, 0, stream>>>(
                bufD, w7b, prm, OFF_SC7, OFF_H7, bufE, 512, 128);
            fc8_kernel<<<Bc / 32, 256, 0, stream>>>(bufE, prm, d_out, c0);
        }
    }
}

// Round 10
// 436.784 us; speedup vs baseline: 1.3739x; 1.0174x over previous
//
#include <hip/hip_runtime.h>

typedef unsigned short bf16_t;
typedef __attribute__((ext_vector_type(8))) short bf16x8;
typedef __attribute__((ext_vector_type(8))) unsigned short u16x8;
typedef __attribute__((ext_vector_type(4))) float f32x4;

#if defined(__has_builtin)
#if __has_builtin(__builtin_amdgcn_global_load_lds)
#define HAS_GLL 1
#endif
#endif

__device__ __forceinline__ float b2f(bf16_t u) {
    return __uint_as_float(((unsigned int)u) << 16);
}
__device__ __forceinline__ bf16_t f2b(float f) {
    unsigned int x = __float_as_uint(f);
    unsigned int r = x + 0x7fffu + ((x >> 16) & 1u);
    return (bf16_t)(r >> 16);
}
__device__ __forceinline__ float ldf(const void* p, int i, int isf) {
    return isf ? ((const float*)p)[i] : b2f(((const bf16_t*)p)[i]);
}

__device__ __forceinline__ void stg16(const bf16_t* g, bf16_t* l) {
#ifdef HAS_GLL
    __builtin_amdgcn_global_load_lds(
        (const __attribute__((address_space(1))) unsigned int*)g,
        (__attribute__((address_space(3))) unsigned int*)l,
        16, 0, 0);
#else
    *(uint4*)l = *(const uint4*)g;
#endif
}

// ---- params block offsets (floats) ----
#define OFF_S0T0 0
#define OFF_W1   16
#define OFF_S1   592
#define OFF_H1   656
#define OFF_S2   720
#define OFF_H2   784
#define OFF_S3   848
#define OFF_H3   912
#define OFF_S4   976
#define OFF_H4   1040
#define OFF_SC5  1104
#define OFF_H5   1112
#define OFF_SC6  1624
#define OFF_H6   1632
#define OFF_SC7  2144
#define OFF_H7   2152
#define OFF_W8   2280
#define OFF_B8   3304
#define OFF_FLAG 4032

// ---------------------------------------------------------------------------
__global__ void detect_kernel(const void* xraw, float* prm)
{
    if (threadIdx.x == 0 && blockIdx.x == 0) {
        const unsigned int* w = (const unsigned int*)xraw;
        int good = 0;
        for (int i = 0; i < 64; i++) {
            float f = __uint_as_float(w[i] << 16);
            float a = fabsf(f);
            if (a >= 0.0009765625f && a <= 16.0f) good++;
        }
        prm[OFF_FLAG] = (good >= 32) ? 0.0f : 1.0f;  // many good => bf16
    }
}

// ---------------------------------------------------------------------------
// ONE setup kernel: all weight permutes/conversions, segmented grid-stride.
// [0,36864) w2 [oc][ic][tap]->[oc][tap*64+ic]
// [36864,561152) w3 [oc][ic][p]->[p][oc*64+ic]
// [561152,1085440) w4 same
// [1085440,5279744) w5 [n][c*128+p]->[n][p*64+c]
// [5279744,5541888) w6 cast
// [5541888,5607424) w7 cast
// ---------------------------------------------------------------------------
__global__ __launch_bounds__(256) void setup_kernel(
    const void* __restrict__ w2, const void* __restrict__ w3,
    const void* __restrict__ w4, const void* __restrict__ w5,
    const void* __restrict__ w6, const void* __restrict__ w7,
    bf16_t* __restrict__ w2p, bf16_t* __restrict__ w3p,
    bf16_t* __restrict__ w4p, bf16_t* __restrict__ w5p,
    bf16_t* __restrict__ w6b, bf16_t* __restrict__ w7b,
    const float* __restrict__ prm)
{
    const int isf = prm[OFF_FLAG] > 0.5f;
    const int i = blockIdx.x * 256 + threadIdx.x;
    if (i < 36864) {
        int oc = i / 576, r = i - oc * 576;
        int tap = r >> 6, ic = r & 63;
        w2p[i] = f2b(ldf(w2, oc * 576 + ic * 9 + tap, isf));
    } else if (i < 561152) {
        int j = i - 36864;
        int p = j >> 12, r = j & 4095;
        int oc = r >> 6, ic = r & 63;
        w3p[j] = f2b(ldf(w3, oc * 8192 + ic * 128 + p, isf));
    } else if (i < 1085440) {
        int j = i - 561152;
        int p = j >> 12, r = j & 4095;
        int oc = r >> 6, ic = r & 63;
        w4p[j] = f2b(ldf(w4, oc * 8192 + ic * 128 + p, isf));
    } else if (i < 5279744) {
        int j = i - 1085440;
        int nr = j >> 13, r = j & 8191;
        int p = r >> 6, c = r & 63;
        w5p[j] = f2b(ldf(w5, nr * 8192 + c * 128 + p, isf));
    } else if (i < 5541888) {
        int j = i - 5279744;
        w6b[j] = isf ? f2b(((const float*)w6)[j]) : ((const bf16_t*)w6)[j];
    } else if (i < 5607424) {
        int j = i - 5541888;
        w7b[j] = isf ? f2b(((const float*)w7)[j]) : ((const bf16_t*)w7)[j];
    }
}

__global__ __launch_bounds__(256) void fold_params_kernel(
    const void* bn0p, const void* w1, const void* b1, const void* bn1p,
    const void* b2c, const void* bn2p, const void* bn3p, const void* bn4p,
    const void* b5, const void* bn5p, const void* b6, const void* bn6p,
    const void* b7, const void* bn7p, const void* w8, const void* b8,
    float* prm)
{
    const int isf = prm[OFF_FLAG] > 0.5f;
    const int t = threadIdx.x;

    if (t == 0) {
        float g = ldf(bn0p, 0, isf), be = ldf(bn0p, 1, isf);
        float m = ldf(bn0p, 2, isf), v = ldf(bn0p, 3, isf);
        float s = g * rsqrtf(v + 1e-5f);
        prm[OFF_S0T0] = s; prm[OFF_S0T0 + 1] = be - m * s;
    }
    for (int i = t; i < 576; i += 256) prm[OFF_W1 + i] = ldf(w1, i, isf);

    if (t < 64) {
        {
            float g = ldf(bn1p, t, isf), be = ldf(bn1p, 64 + t, isf);
            float m = ldf(bn1p, 128 + t, isf), v = ldf(bn1p, 192 + t, isf);
            float s = g * rsqrtf(v + 1e-5f);
            prm[OFF_S1 + t] = s;
            prm[OFF_H1 + t] = s * ldf(b1, t, isf) + (be - m * s);
        }
        {
            float g = ldf(bn2p, t, isf), be = ldf(bn2p, 64 + t, isf);
            float m = ldf(bn2p, 128 + t, isf), v = ldf(bn2p, 192 + t, isf);
            float s = g * rsqrtf(v + 1e-5f);
            prm[OFF_S2 + t] = s;
            prm[OFF_H2 + t] = s * ldf(b2c, t, isf) + (be - m * s);
        }
        {
            float g = ldf(bn3p, t, isf), be = ldf(bn3p, 64 + t, isf);
            float m = ldf(bn3p, 128 + t, isf), v = ldf(bn3p, 192 + t, isf);
            float s = g * rsqrtf(v + 1e-5f);
            prm[OFF_S3 + t] = s;
            prm[OFF_H3 + t] = be - m * s;
        }
        {
            float g = ldf(bn4p, t, isf), be = ldf(bn4p, 64 + t, isf);
            float m = ldf(bn4p, 128 + t, isf), v = ldf(bn4p, 192 + t, isf);
            float s = g * rsqrtf(v + 1e-5f);
            prm[OFF_S4 + t] = s;
            prm[OFF_H4 + t] = be - m * s;
        }
    }
    {
        float g = ldf(bn5p, 0, isf), be = ldf(bn5p, 1, isf);
        float m = ldf(bn5p, 2, isf), v = ldf(bn5p, 3, isf);
        float s = g * rsqrtf(v + 1e-5f);
        if (t == 0) prm[OFF_SC5] = s;
        for (int i = t; i < 512; i += 256)
            prm[OFF_H5 + i] = s * ldf(b5, i, isf) + (be - m * s);
    }
    {
        float g = ldf(bn6p, 0, isf), be = ldf(bn6p, 1, isf);
        float m = ldf(bn6p, 2, isf), v = ldf(bn6p, 3, isf);
        float s = g * rsqrtf(v + 1e-5f);
        if (t == 0) prm[OFF_SC6] = s;
        for (int i = t; i < 512; i += 256)
            prm[OFF_H6 + i] = s * ldf(b6, i, isf) + (be - m * s);
    }
    {
        float g = ldf(bn7p, 0, isf), be = ldf(bn7p, 1, isf);
        float m = ldf(bn7p, 2, isf), v = ldf(bn7p, 3, isf);
        float s = g * rsqrtf(v + 1e-5f);
        if (t == 0) prm[OFF_SC7] = s;
        if (t < 128) prm[OFF_H7 + t] = s * ldf(b7, t, isf) + (be - m * s);
    }
    for (int i = t; i < 1024; i += 256) prm[OFF_W8 + i] = ldf(w8, i, isf);
    if (t < 8) prm[OFF_B8 + t] = ldf(b8, t, isf);
}

// ---------------------------------------------------------------------------
// conv1: transpose+bn0 -> conv1+bn1+relu.  FOUR samples per block.
// Output PIXEL-MAJOR: c1[p][b][ic], bf16.
// ---------------------------------------------------------------------------
__global__ __launch_bounds__(256) void conv1_kernel(
    const void* __restrict__ x, const float* __restrict__ prm,
    bf16_t* __restrict__ c1, int Bc, int c0)
{
    __shared__ float xn[180];
    __shared__ float w1s[576];

    const int t = threadIdx.x;
    const int b0 = blockIdx.x * 4;
    const int isf = prm[OFF_FLAG] > 0.5f;
    const float s0 = prm[OFF_S0T0], t0 = prm[OFF_S0T0 + 1];

    for (int i = t; i < 576; i += 256) w1s[i] = prm[OFF_W1 + i];

    const int pg  = t & 31;
    const int oc0 = (t >> 5) * 8;

    float s1[8], h1[8];
    #pragma unroll
    for (int j = 0; j < 8; j++) {
        s1[j] = prm[OFF_S1 + oc0 + j];
        h1[j] = prm[OFF_H1 + oc0 + j];
    }

    for (int s = 0; s < 4; s++) {
        const int b = b0 + s;
        __syncthreads();
        if (t < 180) {
            int row = t / 18, col = t - row * 18;
            float v = 0.f;
            if (row >= 1 && row <= 8 && col >= 1 && col <= 16)
                v = s0 * ldf(x, (c0 + b) * 128 + (col - 1) * 8 + (row - 1), isf) + t0;
            xn[t] = v;
        }
        __syncthreads();

        #pragma unroll
        for (int m = 0; m < 4; m++) {
            int p = pg + 32 * m;
            int h = p >> 4, w = p & 15;
            float r[9];
            #pragma unroll
            for (int dh = 0; dh < 3; dh++)
                #pragma unroll
                for (int dw = 0; dw < 3; dw++)
                    r[dh * 3 + dw] = xn[(h + dh) * 18 + (w + dw)];
            u16x8 o;
            #pragma unroll
            for (int j = 0; j < 8; j++) {
                float acc = 0.f;
                #pragma unroll
                for (int k = 0; k < 9; k++) acc += r[k] * w1s[(oc0 + j) * 9 + k];
                o[j] = f2b(fmaxf(s1[j] * acc + h1[j], 0.f));
            }
            *(u16x8*)(c1 + (size_t)p * Bc * 64 + (size_t)b * 64 + oc0) = o;
        }
    }
}

// ---------------------------------------------------------------------------
// Fused MFMA: conv2(im2col K=576) + bn2relu -> lc3(K=64) + bn3relu
//             -> lc4(K=64) + bn4relu.  Grid (Bc/256, 128 pixels).
// FULLY UNROLLED 18-step conv2 (constants folded; uniform validity preds),
// hoisted swizzled chunk offsets (step-invariant), lc3/lc4 weights
// REGISTER-PRELOADED at kernel start (global latency hidden under conv2;
// lc sections are ds_write + barrier only).  LDS exactly 40960 B.
// LDS (shorts): As dbuf [0,8192)+[8192,16384); Bs dbuf [16384,18432)+
// [18432,20480); smC [0,18432) stride 72 (alias); lc wt [18432,20480).
// ---------------------------------------------------------------------------
__global__ __launch_bounds__(256) void fused_mfma_kernel(
    const bf16_t* __restrict__ c1, const bf16_t* __restrict__ w2p,
    const bf16_t* __restrict__ w3p, const bf16_t* __restrict__ w4p,
    const float* __restrict__ prm, bf16_t* __restrict__ bufA, int Bc)
{
    __shared__ bf16_t sm[20480];       // exactly 40 KiB
    const int t    = threadIdx.x;
    const int lane = t & 63;
    const int wv   = t >> 6;
    const int m0   = blockIdx.x * 256;
    const int p    = blockIdx.y;
    const int h    = p >> 4, w = p & 15;

    const int fr = lane & 15;
    const int fg = lane >> 4;
    const int swz4 = (fr >> 1) & 3;
    const int orow = fg * 4;
    const int ocol = fr;

    // hoisted staging coords (chunk t+256u: +256 leaves low 8 bits intact,
    // so swizzle term is u-invariant; A src offset = coff0 + 4096u)
    const int gS    = (t & 3) ^ ((t >> 3) & 3);
    const int rA    = t >> 2;
    const int coff0 = rA * 64 + gS * 8;
    const int w2off = rA * 576 + gS * 8;

    // lc3/lc4 weights -> registers now; consumed via ds_write much later
    u16x8 wr3[2], wr4[2];
    {
        const bf16_t* w3b = w3p + (size_t)p * 4096 + coff0;
        const bf16_t* w4b = w4p + (size_t)p * 4096 + coff0;
        wr3[0] = *(const u16x8*)(w3b);
        wr3[1] = *(const u16x8*)(w3b + 32);
        wr4[0] = *(const u16x8*)(w4b);
        wr4[1] = *(const u16x8*)(w4b + 32);
    }

    f32x4 acc[4][4];
    #pragma unroll
    for (int i = 0; i < 4; i++)
        #pragma unroll
        for (int j = 0; j < 4; j++)
            acc[i][j] = (f32x4){0.f, 0.f, 0.f, 0.f};

    const bf16_t* c1b = c1 + (size_t)m0 * 64 + coff0;
    const size_t planeStride = (size_t)Bc * 64;

    // ---------------- conv2: fully unrolled dbuf pipeline, 18 k-steps ----------------
    {   // prologue: stage step 0 (tap 0 = (-1,-1)) if valid
        if (h > 0 && w > 0) {
            const bf16_t* ab = c1b + (size_t)((h - 1) * 16 + (w - 1)) * planeStride;
            #pragma unroll
            for (int u = 0; u < 4; u++)
                stg16(ab + u * 4096, sm + t * 8 + u * 2048);
            stg16(w2p + w2off, sm + 16384 + t * 8);
        }
    }
    #pragma unroll
    for (int s = 0; s < 18; s++) {
        const int cur = s & 1;
        __syncthreads();
        if (s + 1 < 18) {
            const int s1  = s + 1;
            const int tap = s1 >> 1;
            const int dh = tap / 3 - 1, dw = tap % 3 - 1;   // compile-time
            const int hh = h + dh, ww = w + dw;
            if (hh >= 0 && hh < 8 && ww >= 0 && ww < 16) {  // uniform
                const int nb  = cur ^ 1;
                const int ic0 = (s1 & 1) * 32;
                const bf16_t* ab = c1b + (size_t)(hh * 16 + ww) * planeStride + ic0;
                #pragma unroll
                for (int u = 0; u < 4; u++)
                    stg16(ab + u * 4096, sm + nb * 8192 + t * 8 + u * 2048);
                stg16(w2p + w2off + tap * 64 + ic0, sm + 16384 + nb * 2048 + t * 8);
            }
        }
        {
            const int tap = s >> 1;
            const int dh = tap / 3 - 1, dw = tap % 3 - 1;   // compile-time
            const int hh = h + dh, ww = w + dw;
            if (hh >= 0 && hh < 8 && ww >= 0 && ww < 16) {  // uniform
                const bf16_t* Ab = sm + cur * 8192;
                const bf16_t* Bb = sm + 16384 + cur * 2048;
                bf16x8 af[4], bf[4];
                #pragma unroll
                for (int i = 0; i < 4; i++)
                    af[i] = *(const bf16x8*)(Ab + ((wv * 64 + i * 16 + fr) * 4 + (fg ^ swz4)) * 8);
                #pragma unroll
                for (int j = 0; j < 4; j++)
                    bf[j] = *(const bf16x8*)(Bb + ((j * 16 + fr) * 4 + (fg ^ swz4)) * 8);
                #pragma unroll
                for (int i = 0; i < 4; i++)
                    #pragma unroll
                    for (int j = 0; j < 4; j++)
                        acc[i][j] = __builtin_amdgcn_mfma_f32_16x16x32_bf16(
                            af[i], bf[j], acc[i][j], 0, 0, 0);
            }
        }
    }
    __syncthreads();   // all conv2 LDS reads done (incl. Bs buf1 = lc wt region)

    // conv2 epilogue -> smC (each wave writes only its own 64-row band)
    // + stage lc3 ks0 weights from registers
    #pragma unroll
    for (int j = 0; j < 4; j++) {
        const int oc = j * 16 + ocol;
        const float s = prm[OFF_S2 + oc], hh2 = prm[OFF_H2 + oc];
        #pragma unroll
        for (int i = 0; i < 4; i++) {
            const int rb = wv * 64 + i * 16 + orow;
            #pragma unroll
            for (int r = 0; r < 4; r++)
                sm[(rb + r) * 72 + oc] = f2b(fmaxf(s * acc[i][j][r] + hh2, 0.f));
        }
    }
    *(u16x8*)(sm + 18432 + t * 8) = wr3[0];
    __syncthreads();

    // ---------------- lc3: K=64 (2 halves, weights from registers) ----------------
    #pragma unroll
    for (int i = 0; i < 4; i++)
        #pragma unroll
        for (int j = 0; j < 4; j++)
            acc[i][j] = (f32x4){0.f, 0.f, 0.f, 0.f};

    #pragma unroll
    for (int ks = 0; ks < 2; ks++) {
        if (ks == 1) {
            __syncthreads();                       // all ks0 B-reads done
            *(u16x8*)(sm + 18432 + t * 8) = wr3[1];
            __syncthreads();
        }
        bf16x8 af[4], bf[4];
        #pragma unroll
        for (int i = 0; i < 4; i++)
            af[i] = *(const bf16x8*)(sm + (wv * 64 + i * 16 + fr) * 72 + ks * 32 + fg * 8);
        #pragma unroll
        for (int j = 0; j < 4; j++)
            bf[j] = *(const bf16x8*)(sm + 18432 + ((j * 16 + fr) * 4 + (fg ^ swz4)) * 8);
        #pragma unroll
        for (int i = 0; i < 4; i++)
            #pragma unroll
            for (int j = 0; j < 4; j++)
                acc[i][j] = __builtin_amdgcn_mfma_f32_16x16x32_bf16(
                    af[i], bf[j], acc[i][j], 0, 0, 0);
    }

    // lc3 epilogue (own band, no cross-wave smC hazard)
    #pragma unroll
    for (int j = 0; j < 4; j++) {
        const int oc = j * 16 + ocol;
        const float s = prm[OFF_S3 + oc], hh3 = prm[OFF_H3 + oc];
        #pragma unroll
        for (int i = 0; i < 4; i++) {
            const int rb = wv * 64 + i * 16 + orow;
            #pragma unroll
            for (int r = 0; r < 4; r++)
                sm[(rb + r) * 72 + oc] = f2b(fmaxf(s * acc[i][j][r] + hh3, 0.f));
        }
    }
    __syncthreads();                               // lc3 ks1 B-reads done
    *(u16x8*)(sm + 18432 + t * 8) = wr4[0];
    __syncthreads();

    // ---------------- lc4: K=64 ----------------
    #pragma unroll
    for (int i = 0; i < 4; i++)
        #pragma unroll
        for (int j = 0; j < 4; j++)
            acc[i][j] = (f32x4){0.f, 0.f, 0.f, 0.f};

    #pragma unroll
    for (int ks = 0; ks < 2; ks++) {
        if (ks == 1) {
            __syncthreads();
            *(u16x8*)(sm + 18432 + t * 8) = wr4[1];
            __syncthreads();
        }
        bf16x8 af[4], bf[4];
        #pragma unroll
        for (int i = 0; i < 4; i++)
            af[i] = *(const bf16x8*)(sm + (wv * 64 + i * 16 + fr) * 72 + ks * 32 + fg * 8);
        #pragma unroll
        for (int j = 0; j < 4; j++)
            bf[j] = *(const bf16x8*)(sm + 18432 + ((j * 16 + fr) * 4 + (fg ^ swz4)) * 8);
        #pragma unroll
        for (int i = 0; i < 4; i++)
            #pragma unroll
            for (int j = 0; j < 4; j++)
                acc[i][j] = __builtin_amdgcn_mfma_f32_16x16x32_bf16(
                    af[i], bf[j], acc[i][j], 0, 0, 0);
    }

    // lc4 epilogue -> smC (own band), then barrier, then coalesced bufA write
    #pragma unroll
    for (int j = 0; j < 4; j++) {
        const int oc = j * 16 + ocol;
        const float s = prm[OFF_S4 + oc], hh4 = prm[OFF_H4 + oc];
        #pragma unroll
        for (int i = 0; i < 4; i++) {
            const int rb = wv * 64 + i * 16 + orow;
            #pragma unroll
            for (int r = 0; r < 4; r++)
                sm[(rb + r) * 72 + oc] = f2b(fmaxf(s * acc[i][j][r] + hh4, 0.f));
        }
    }
    __syncthreads();

    const int wrow = t >> 3, wc0 = (t & 7) * 8;
    #pragma unroll
    for (int pass = 0; pass < 8; pass++) {
        const int row = wrow + pass * 32;
        *(uint4*)(bufA + (size_t)(m0 + row) * 8192 + p * 64 + wc0) =
            *(const uint4*)(sm + row * 72 + wc0);
    }
}

// ---------------------------------------------------------------------------
// MFMA GEMM: out[M][N] = relu(s*(A.W^T)+shift), bf16.
// BM=128, BN=64, BK=64.  4 waves 2x2, wave tile 64x32, 16 MFMA per barrier.
// XOR-swizzled chunks -> coalesced gll staging + free 2-way b128 frag reads.
// 1-deep dbuf, 1 barrier per k-step.  48 KiB LDS.
// ---------------------------------------------------------------------------
__global__ __launch_bounds__(256) void gemm_mfma(
    const bf16_t* __restrict__ A, const bf16_t* __restrict__ W,
    const float* __restrict__ prm, int sc_off, int sh_off,
    bf16_t* __restrict__ out, int K, int N)
{
    __shared__ bf16_t sm[24576];
    const int t    = threadIdx.x;
    const int lane = t & 63;
    const int wv   = t >> 6;
    const int wr   = wv >> 1, wc = wv & 1;
    const int m0   = blockIdx.x * 128, n0 = blockIdx.y * 64;

    const int fr = lane & 15;
    const int fg = lane >> 4;
    const int swz8 = fr & 7;

    const bf16_t* srcA[4]; bf16_t* dstA[4];
    #pragma unroll
    for (int u = 0; u < 4; u++) {
        const int c = t + 256 * u;
        const int row = c >> 3;
        const int g = (c & 7) ^ (row & 7);
        srcA[u] = A + (size_t)(m0 + row) * K + g * 8;
        dstA[u] = sm + c * 8;
    }
    const bf16_t* srcB[2]; bf16_t* dstB[2];
    #pragma unroll
    for (int u = 0; u < 2; u++) {
        const int c = t + 256 * u;
        const int row = c >> 3;
        const int g = (c & 7) ^ (row & 7);
        srcB[u] = W + (size_t)(n0 + row) * K + g * 8;
        dstB[u] = sm + 16384 + c * 8;
    }

    f32x4 acc[4][2];
    #pragma unroll
    for (int i = 0; i < 4; i++)
        #pragma unroll
        for (int j = 0; j < 2; j++)
            acc[i][j] = (f32x4){0.f, 0.f, 0.f, 0.f};

    const int KS = K >> 6;

    #pragma unroll
    for (int u = 0; u < 4; u++) stg16(srcA[u], dstA[u]);
    #pragma unroll
    for (int u = 0; u < 2; u++) stg16(srcB[u], dstB[u]);

    for (int ks = 0; ks < KS; ks++) {
        const int cur = ks & 1;
        __syncthreads();
        if (ks + 1 < KS) {
            const int nb = cur ^ 1;
            const int kk = (ks + 1) << 6;
            #pragma unroll
            for (int u = 0; u < 4; u++) stg16(srcA[u] + kk, dstA[u] + nb * 8192);
            #pragma unroll
            for (int u = 0; u < 2; u++) stg16(srcB[u] + kk, dstB[u] + nb * 4096);
        }
        const bf16_t* Ab = sm + cur * 8192;
        const bf16_t* Bb = sm + 16384 + cur * 4096;
        bf16x8 af[4][2], bf2[2][2];
        #pragma unroll
        for (int i = 0; i < 4; i++)
            #pragma unroll
            for (int hh = 0; hh < 2; hh++) {
                const int r = wr * 64 + i * 16 + fr;
                const int g = hh * 4 + fg;
                af[i][hh] = *(const bf16x8*)(Ab + (r * 8 + (g ^ swz8)) * 8);
            }
        #pragma unroll
        for (int j = 0; j < 2; j++)
            #pragma unroll
            for (int hh = 0; hh < 2; hh++) {
                const int r = wc * 32 + j * 16 + fr;
                const int g = hh * 4 + fg;
                bf2[j][hh] = *(const bf16x8*)(Bb + (r * 8 + (g ^ swz8)) * 8);
            }
        #pragma unroll
        for (int hh = 0; hh < 2; hh++)
            #pragma unroll
            for (int i = 0; i < 4; i++)
                #pragma unroll
                for (int j = 0; j < 2; j++)
                    acc[i][j] = __builtin_amdgcn_mfma_f32_16x16x32_bf16(
                        af[i][hh], bf2[j][hh], acc[i][j], 0, 0, 0);
    }

    const float s    = prm[sc_off];
    const int   orow = fg * 4;
    const int   ocol = fr;
    #pragma unroll
    for (int j = 0; j < 2; j++) {
        const int n  = n0 + wc * 32 + j * 16 + ocol;
        const float sh = prm[sh_off + n];
        #pragma unroll
        for (int i = 0; i < 4; i++) {
            const int mb = m0 + wr * 64 + i * 16 + orow;
            #pragma unroll
            for (int r = 0; r < 4; r++) {
                float v = fmaxf(s * acc[i][j][r] + sh, 0.f);
                out[(size_t)(mb + r) * N + n] = f2b(v);
            }
        }
    }
}

// ---------------------------------------------------------------------------
// fc8: out[b][n] = h[b][:] . w8[n][:] + b8[n]   (N=8, K=128), h is bf16
// ---------------------------------------------------------------------------
__global__ __launch_bounds__(256) void fc8_kernel(
    const bf16_t* __restrict__ h, const float* __restrict__ prm,
    void* __restrict__ out, int c0)
{
    __shared__ float wsm[8 * 129];
    const int t = threadIdx.x;
    for (int i = t; i < 1024; i += 256) {
        int n = i >> 7, k = i & 127;
        wsm[n * 129 + k] = prm[OFF_W8 + i];
    }
    __syncthreads();
    const int isf = prm[OFF_FLAG] > 0.5f;
    const int bl = t >> 3, n = t & 7;
    const int b = c0 + blockIdx.x * 32 + bl;
    const bf16_t* hb = h + (size_t)(blockIdx.x * 32 + bl) * 128;
    float acc = prm[OFF_B8 + n];
    for (int k = 0; k < 128; k++) acc += b2f(hb[k]) * wsm[n * 129 + k];
    if (isf) ((float*)out)[(size_t)b * 8 + n] = acc;
    else     ((bf16_t*)out)[(size_t)b * 8 + n] = f2b(acc);
}

// ---------------------------------------------------------------------------
extern "C" void kernel_launch(void* const* d_in, const int* in_sizes, int n_in,
                              void* d_out, int out_size, void* d_ws, size_t ws_size,
                              hipStream_t stream)
{
    const void* x    = d_in[0];
    const void* bn0p = d_in[1];
    const void* w1   = d_in[2];
    const void* b1   = d_in[3];
    const void* bn1p = d_in[4];
    const void* w2   = d_in[5];
    const void* b2c  = d_in[6];
    const void* bn2p = d_in[7];
    const void* w3   = d_in[8];
    const void* bn3p = d_in[9];
    const void* w4   = d_in[10];
    const void* bn4p = d_in[11];
    const void* w5   = d_in[12];
    const void* b5   = d_in[13];
    const void* bn5p = d_in[14];
    const void* w6   = d_in[15];
    const void* b6   = d_in[16];
    const void* bn6p = d_in[17];
    const void* w7   = d_in[18];
    const void* b7   = d_in[19];
    const void* bn7p = d_in[20];
    const void* w8   = d_in[21];
    const void* b8   = d_in[22];

    char* base = (char*)d_ws;
    float*  prm = (float*)(base + 0);            //    16384 B
    bf16_t* w2p = (bf16_t*)(base + 16384);       //    73728 B
    bf16_t* w3p = (bf16_t*)(base + 90112);       //  1048576 B
    bf16_t* w4p = (bf16_t*)(base + 1138688);     //  1048576 B
    bf16_t* w5p = (bf16_t*)(base + 2187264);     //  8388608 B
    bf16_t* w6b = (bf16_t*)(base + 10575872);    //   524288 B
    bf16_t* w7b = (bf16_t*)(base + 11100160);    //   131072 B
    char*   acts = base + 11231232;

    const int B = 8192;
    const size_t FIXED = 11231232ull;

    detect_kernel<<<1, 64, 0, stream>>>(x, prm);
    fold_params_kernel<<<1, 256, 0, stream>>>(
        bn0p, w1, b1, bn1p, b2c, bn2p, bn3p, bn4p,
        b5, bn5p, b6, bn6p, b7, bn7p, w8, b8, prm);
    setup_kernel<<<21904, 256, 0, stream>>>(
        w2, w3, w4, w5, w6, w7, w2p, w3p, w4p, w5p, w6b, w7b, prm);

    const int Bf = 4096;
    const size_t FULL_NEED = FIXED + (size_t)Bf * 16384ull + (size_t)B * 18688ull;

    if (ws_size >= FULL_NEED) {
        bf16_t* c1   = (bf16_t*)acts;                    // [128][Bf][64]
        bf16_t* bufA = c1 + (size_t)Bf * 8192;           // [B][8192]
        bf16_t* bufC = bufA + (size_t)B * 8192;          // [B][512]
        bf16_t* bufD = bufC + (size_t)B * 512;           // [B][512]
        bf16_t* bufE = bufD + (size_t)B * 512;           // [B][128]

        for (int c0 = 0; c0 < B; c0 += Bf) {
            conv1_kernel<<<Bf / 4, 256, 0, stream>>>(x, prm, c1, Bf, c0);
            fused_mfma_kernel<<<dim3(Bf / 256, 128), 256, 0, stream>>>(
                c1, w2p, w3p, w4p, prm, bufA + (size_t)c0 * 8192, Bf);
        }
        gemm_mfma<<<dim3(B / 128, 8), 256, 0, stream>>>(
            bufA, w5p, prm, OFF_SC5, OFF_H5, bufC, 8192, 512);
        gemm_mfma<<<dim3(B / 128, 8), 256, 0, stream>>>(
            bufC, w6b, prm, OFF_SC6, OFF_H6, bufD, 512, 512);
        gemm_mfma<<<dim3(B / 128, 2), 256, 0, stream>>>(
            bufD, w7b, prm, OFF_SC7, OFF_H7, bufE, 512, 128);
        fc8_kernel<<<B / 32, 256, 0, stream>>>(bufE, prm, d_out, 0);
    } else {
        size_t avail = (ws_size > FIXED) ? (ws_size - FIXED) : 0;
        int Bc = 8192;
        while (Bc > 256 && (size_t)Bc * 35072ull > avail) Bc >>= 1;

        bf16_t* c1   = (bf16_t*)acts;
        bf16_t* bufA = c1 + (size_t)Bc * 8192;
        bf16_t* bufC = bufA + (size_t)Bc * 8192;
        bf16_t* bufD = bufC + (size_t)Bc * 512;
        bf16_t* bufE = bufD + (size_t)Bc * 512;

        for (int c0 = 0; c0 < B; c0 += Bc) {
            conv1_kernel<<<Bc / 4, 256, 0, stream>>>(x, prm, c1, Bc, c0);
            fused_mfma_kernel<<<dim3(Bc / 256, 128), 256, 0, stream>>>(
                c1, w2p, w3p, w4p, prm, bufA, Bc);
            gemm_mfma<<<dim3(Bc / 128, 8), 256, 0, stream>>>(
                bufA, w5p, prm, OFF_SC5, OFF_H5, bufC, 8192, 512);
            gemm_mfma<<<dim3(Bc / 128, 8), 256, 0, stream>>>(
                bufC, w6b, prm, OFF_SC6, OFF_H6, bufD, 512, 512);
            gemm_mfma<<<dim3(Bc / 128, 2), 256, 0, stream>>>(
                bufD, w7b, prm, OFF_SC7, OFF_H7, bufE, 512, 128);
            fc8_kernel<<<Bc / 32, 256, 0, stream>>>(bufE, prm, d_out, c0);
        }
    }
}

// Round 11
// 427.811 us; speedup vs baseline: 1.4028x; 1.0210x over previous
//
#include <hip/hip_runtime.h>
#include <hip/hip_bf16.h>

typedef unsigned short bf16_t;
typedef __attribute__((ext_vector_type(8))) short bf16x8;
typedef __attribute__((ext_vector_type(8))) unsigned short u16x8;
typedef __attribute__((ext_vector_type(4))) float f32x4;

#if defined(__has_builtin)
#if __has_builtin(__builtin_amdgcn_global_load_lds)
#define HAS_GLL 1
#endif
#endif

__device__ __forceinline__ float b2f(bf16_t u) {
    return __uint_as_float(((unsigned int)u) << 16);
}
__device__ __forceinline__ bf16_t f2b(float f) {
    unsigned int x = __float_as_uint(f);
    unsigned int r = x + 0x7fffu + ((x >> 16) & 1u);
    return (bf16_t)(r >> 16);
}
// packed 2x f32 -> bf16x2 (RNE, matches f2b)
__device__ __forceinline__ unsigned int pk2(float a, float b) {
    __hip_bfloat162 t = __float22bfloat162_rn(make_float2(a, b));
    return *(unsigned int*)&t;
}
__device__ __forceinline__ float ldf(const void* p, int i, int isf) {
    return isf ? ((const float*)p)[i] : b2f(((const bf16_t*)p)[i]);
}

__device__ __forceinline__ void stg16(const bf16_t* g, bf16_t* l) {
#ifdef HAS_GLL
    __builtin_amdgcn_global_load_lds(
        (const __attribute__((address_space(1))) unsigned int*)g,
        (__attribute__((address_space(3))) unsigned int*)l,
        16, 0, 0);
#else
    *(uint4*)l = *(const uint4*)g;
#endif
}

// ---- params block offsets (floats) ----
#define OFF_S0T0 0
#define OFF_W1   16
#define OFF_S1   592
#define OFF_H1   656
#define OFF_S2   720
#define OFF_H2   784
#define OFF_S3   848
#define OFF_H3   912
#define OFF_S4   976
#define OFF_H4   1040
#define OFF_SC5  1104
#define OFF_H5   1112
#define OFF_SC6  1624
#define OFF_H6   1632
#define OFF_SC7  2144
#define OFF_H7   2152
#define OFF_W8   2280
#define OFF_B8   3304
#define OFF_FLAG 4032

// ---------------------------------------------------------------------------
// ONE setup kernel: all weight permutes/conversions, segmented grid-stride.
// ---------------------------------------------------------------------------
__global__ __launch_bounds__(256) void setup_kernel(
    const void* __restrict__ w2, const void* __restrict__ w3,
    const void* __restrict__ w4, const void* __restrict__ w5,
    const void* __restrict__ w6, const void* __restrict__ w7,
    bf16_t* __restrict__ w2p, bf16_t* __restrict__ w3p,
    bf16_t* __restrict__ w4p, bf16_t* __restrict__ w5p,
    bf16_t* __restrict__ w6b, bf16_t* __restrict__ w7b,
    const float* __restrict__ prm)
{
    const int isf = prm[OFF_FLAG] > 0.5f;
    const int i = blockIdx.x * 256 + threadIdx.x;
    if (i < 36864) {
        int oc = i / 576, r = i - oc * 576;
        int tap = r >> 6, ic = r & 63;
        w2p[i] = f2b(ldf(w2, oc * 576 + ic * 9 + tap, isf));
    } else if (i < 561152) {
        int j = i - 36864;
        int p = j >> 12, r = j & 4095;
        int oc = r >> 6, ic = r & 63;
        w3p[j] = f2b(ldf(w3, oc * 8192 + ic * 128 + p, isf));
    } else if (i < 1085440) {
        int j = i - 561152;
        int p = j >> 12, r = j & 4095;
        int oc = r >> 6, ic = r & 63;
        w4p[j] = f2b(ldf(w4, oc * 8192 + ic * 128 + p, isf));
    } else if (i < 5279744) {
        int j = i - 1085440;
        int nr = j >> 13, r = j & 8191;
        int p = r >> 6, c = r & 63;
        w5p[j] = f2b(ldf(w5, nr * 8192 + c * 128 + p, isf));
    } else if (i < 5541888) {
        int j = i - 5279744;
        w6b[j] = isf ? f2b(((const float*)w6)[j]) : ((const bf16_t*)w6)[j];
    } else if (i < 5607424) {
        int j = i - 5541888;
        w7b[j] = isf ? f2b(((const float*)w7)[j]) : ((const bf16_t*)w7)[j];
    }
}

// detect (bf16 vs fp32 storage) + fold all BN params, one kernel.
__global__ __launch_bounds__(256) void fold_params_kernel(
    const void* xraw,
    const void* bn0p, const void* w1, const void* b1, const void* bn1p,
    const void* b2c, const void* bn2p, const void* bn3p, const void* bn4p,
    const void* b5, const void* bn5p, const void* b6, const void* bn6p,
    const void* b7, const void* bn7p, const void* w8, const void* b8,
    float* prm)
{
    __shared__ float sflag;
    const int t = threadIdx.x;
    if (t == 0) {
        const unsigned int* w = (const unsigned int*)xraw;
        int good = 0;
        for (int i = 0; i < 64; i++) {
            float f = __uint_as_float(w[i] << 16);
            float a = fabsf(f);
            if (a >= 0.0009765625f && a <= 16.0f) good++;
        }
        float fl = (good >= 32) ? 0.0f : 1.0f;   // many good => bf16
        sflag = fl;
        prm[OFF_FLAG] = fl;
    }
    __syncthreads();
    const int isf = sflag > 0.5f;

    if (t == 0) {
        float g = ldf(bn0p, 0, isf), be = ldf(bn0p, 1, isf);
        float m = ldf(bn0p, 2, isf), v = ldf(bn0p, 3, isf);
        float s = g * rsqrtf(v + 1e-5f);
        prm[OFF_S0T0] = s; prm[OFF_S0T0 + 1] = be - m * s;
    }
    for (int i = t; i < 576; i += 256) prm[OFF_W1 + i] = ldf(w1, i, isf);

    if (t < 64) {
        {
            float g = ldf(bn1p, t, isf), be = ldf(bn1p, 64 + t, isf);
            float m = ldf(bn1p, 128 + t, isf), v = ldf(bn1p, 192 + t, isf);
            float s = g * rsqrtf(v + 1e-5f);
            prm[OFF_S1 + t] = s;
            prm[OFF_H1 + t] = s * ldf(b1, t, isf) + (be - m * s);
        }
        {
            float g = ldf(bn2p, t, isf), be = ldf(bn2p, 64 + t, isf);
            float m = ldf(bn2p, 128 + t, isf), v = ldf(bn2p, 192 + t, isf);
            float s = g * rsqrtf(v + 1e-5f);
            prm[OFF_S2 + t] = s;
            prm[OFF_H2 + t] = s * ldf(b2c, t, isf) + (be - m * s);
        }
        {
            float g = ldf(bn3p, t, isf), be = ldf(bn3p, 64 + t, isf);
            float m = ldf(bn3p, 128 + t, isf), v = ldf(bn3p, 192 + t, isf);
            float s = g * rsqrtf(v + 1e-5f);
            prm[OFF_S3 + t] = s;
            prm[OFF_H3 + t] = be - m * s;
        }
        {
            float g = ldf(bn4p, t, isf), be = ldf(bn4p, 64 + t, isf);
            float m = ldf(bn4p, 128 + t, isf), v = ldf(bn4p, 192 + t, isf);
            float s = g * rsqrtf(v + 1e-5f);
            prm[OFF_S4 + t] = s;
            prm[OFF_H4 + t] = be - m * s;
        }
    }
    {
        float g = ldf(bn5p, 0, isf), be = ldf(bn5p, 1, isf);
        float m = ldf(bn5p, 2, isf), v = ldf(bn5p, 3, isf);
        float s = g * rsqrtf(v + 1e-5f);
        if (t == 0) prm[OFF_SC5] = s;
        for (int i = t; i < 512; i += 256)
            prm[OFF_H5 + i] = s * ldf(b5, i, isf) + (be - m * s);
    }
    {
        float g = ldf(bn6p, 0, isf), be = ldf(bn6p, 1, isf);
        float m = ldf(bn6p, 2, isf), v = ldf(bn6p, 3, isf);
        float s = g * rsqrtf(v + 1e-5f);
        if (t == 0) prm[OFF_SC6] = s;
        for (int i = t; i < 512; i += 256)
            prm[OFF_H6 + i] = s * ldf(b6, i, isf) + (be - m * s);
    }
    {
        float g = ldf(bn7p, 0, isf), be = ldf(bn7p, 1, isf);
        float m = ldf(bn7p, 2, isf), v = ldf(bn7p, 3, isf);
        float s = g * rsqrtf(v + 1e-5f);
        if (t == 0) prm[OFF_SC7] = s;
        if (t < 128) prm[OFF_H7 + t] = s * ldf(b7, t, isf) + (be - m * s);
    }
    for (int i = t; i < 1024; i += 256) prm[OFF_W8 + i] = ldf(w8, i, isf);
    if (t < 8) prm[OFF_B8 + t] = ldf(b8, t, isf);
}

// ---------------------------------------------------------------------------
// conv1: transpose+bn0 -> conv1+bn1+relu.  FOUR samples per block.
// Output PIXEL-MAJOR: c1[p][b][ic], bf16.
// ---------------------------------------------------------------------------
__global__ __launch_bounds__(256) void conv1_kernel(
    const void* __restrict__ x, const float* __restrict__ prm,
    bf16_t* __restrict__ c1, int Bc, int c0)
{
    __shared__ float xn[180];
    __shared__ float w1s[576];

    const int t = threadIdx.x;
    const int b0 = blockIdx.x * 4;
    const int isf = prm[OFF_FLAG] > 0.5f;
    const float s0 = prm[OFF_S0T0], t0 = prm[OFF_S0T0 + 1];

    for (int i = t; i < 576; i += 256) w1s[i] = prm[OFF_W1 + i];

    const int pg  = t & 31;
    const int oc0 = (t >> 5) * 8;

    float s1[8], h1[8];
    #pragma unroll
    for (int j = 0; j < 8; j++) {
        s1[j] = prm[OFF_S1 + oc0 + j];
        h1[j] = prm[OFF_H1 + oc0 + j];
    }

    for (int s = 0; s < 4; s++) {
        const int b = b0 + s;
        __syncthreads();
        if (t < 180) {
            int row = t / 18, col = t - row * 18;
            float v = 0.f;
            if (row >= 1 && row <= 8 && col >= 1 && col <= 16)
                v = s0 * ldf(x, (c0 + b) * 128 + (col - 1) * 8 + (row - 1), isf) + t0;
            xn[t] = v;
        }
        __syncthreads();

        #pragma unroll
        for (int m = 0; m < 4; m++) {
            int p = pg + 32 * m;
            int h = p >> 4, w = p & 15;
            float r[9];
            #pragma unroll
            for (int dh = 0; dh < 3; dh++)
                #pragma unroll
                for (int dw = 0; dw < 3; dw++)
                    r[dh * 3 + dw] = xn[(h + dh) * 18 + (w + dw)];
            u16x8 o;
            #pragma unroll
            for (int j = 0; j < 8; j++) {
                float acc = 0.f;
                #pragma unroll
                for (int k = 0; k < 9; k++) acc += r[k] * w1s[(oc0 + j) * 9 + k];
                o[j] = f2b(fmaxf(s1[j] * acc + h1[j], 0.f));
            }
            *(u16x8*)(c1 + (size_t)p * Bc * 64 + (size_t)b * 64 + oc0) = o;
        }
    }
}

// ---------------------------------------------------------------------------
// Fused MFMA: conv2(im2col K=576) + bn2relu -> lc3(K=64) + bn3relu
//             -> lc4(K=64) + bn4relu.  Grid (Bc/256, 128 pixels).
// OPERAND-SWAPPED MFMA: weights = A (m=oc), activations = B (n=batch), so
// each lane's 4 acc values are 4 CONTIGUOUS oc -> epilogue = packed bf16x2
// cvt + one ds_write_b64 (16 writes vs 64 scalar b16) + float4 BN loads.
// Fragment read addressing is unchanged (A/B layouts are symmetric).
// LDS exactly 40960 B.  18-step unrolled dbuf conv2, uniform validity preds,
// lc3/lc4 weights register-preloaded.
// ---------------------------------------------------------------------------
__global__ __launch_bounds__(256) void fused_mfma_kernel(
    const bf16_t* __restrict__ c1, const bf16_t* __restrict__ w2p,
    const bf16_t* __restrict__ w3p, const bf16_t* __restrict__ w4p,
    const float* __restrict__ prm, bf16_t* __restrict__ bufA, int Bc)
{
    __shared__ bf16_t sm[20480];       // exactly 40 KiB
    const int t    = threadIdx.x;
    const int lane = t & 63;
    const int wv   = t >> 6;
    const int m0   = blockIdx.x * 256;
    const int p    = blockIdx.y;
    const int h    = p >> 4, w = p & 15;

    const int fr = lane & 15;
    const int fg = lane >> 4;
    const int swz4 = (fr >> 1) & 3;

    // hoisted staging coords
    const int gS    = (t & 3) ^ ((t >> 3) & 3);
    const int rA    = t >> 2;
    const int coff0 = rA * 64 + gS * 8;
    const int w2off = rA * 576 + gS * 8;

    // lc3/lc4 weights -> registers now; consumed via ds_write much later
    u16x8 wr3[2], wr4[2];
    {
        const bf16_t* w3b = w3p + (size_t)p * 4096 + coff0;
        const bf16_t* w4b = w4p + (size_t)p * 4096 + coff0;
        wr3[0] = *(const u16x8*)(w3b);
        wr3[1] = *(const u16x8*)(w3b + 32);
        wr4[0] = *(const u16x8*)(w4b);
        wr4[1] = *(const u16x8*)(w4b + 32);
    }

    // acc[i][j]: i = oc tile (M), j = batch tile (N) within wave's 64-row band
    f32x4 acc[4][4];
    #pragma unroll
    for (int i = 0; i < 4; i++)
        #pragma unroll
        for (int j = 0; j < 4; j++)
            acc[i][j] = (f32x4){0.f, 0.f, 0.f, 0.f};

    const bf16_t* c1b = c1 + (size_t)m0 * 64 + coff0;
    const size_t planeStride = (size_t)Bc * 64;

    // ---------------- conv2: fully unrolled dbuf pipeline, 18 k-steps ----------------
    {   // prologue: stage step 0 (tap 0 = (-1,-1)) if valid
        if (h > 0 && w > 0) {
            const bf16_t* ab = c1b + (size_t)((h - 1) * 16 + (w - 1)) * planeStride;
            #pragma unroll
            for (int u = 0; u < 4; u++)
                stg16(ab + u * 4096, sm + t * 8 + u * 2048);
            stg16(w2p + w2off, sm + 16384 + t * 8);
        }
    }
    #pragma unroll
    for (int s = 0; s < 18; s++) {
        const int cur = s & 1;
        __syncthreads();
        if (s + 1 < 18) {
            const int s1  = s + 1;
            const int tap = s1 >> 1;
            const int dh = tap / 3 - 1, dw = tap % 3 - 1;   // compile-time
            const int hh = h + dh, ww = w + dw;
            if (hh >= 0 && hh < 8 && ww >= 0 && ww < 16) {  // uniform
                const int nb  = cur ^ 1;
                const int ic0 = (s1 & 1) * 32;
                const bf16_t* ab = c1b + (size_t)(hh * 16 + ww) * planeStride + ic0;
                #pragma unroll
                for (int u = 0; u < 4; u++)
                    stg16(ab + u * 4096, sm + nb * 8192 + t * 8 + u * 2048);
                stg16(w2p + w2off + tap * 64 + ic0, sm + 16384 + nb * 2048 + t * 8);
            }
        }
        {
            const int tap = s >> 1;
            const int dh = tap / 3 - 1, dw = tap % 3 - 1;   // compile-time
            const int hh = h + dh, ww = w + dw;
            if (hh >= 0 && hh < 8 && ww >= 0 && ww < 16) {  // uniform
                const bf16_t* Ab = sm + cur * 8192;            // activations
                const bf16_t* Bb = sm + 16384 + cur * 2048;    // weights
                bf16x8 hf[4], wf[4];
                #pragma unroll
                for (int j = 0; j < 4; j++)
                    hf[j] = *(const bf16x8*)(Ab + ((wv * 64 + j * 16 + fr) * 4 + (fg ^ swz4)) * 8);
                #pragma unroll
                for (int i = 0; i < 4; i++)
                    wf[i] = *(const bf16x8*)(Bb + ((i * 16 + fr) * 4 + (fg ^ swz4)) * 8);
                #pragma unroll
                for (int i = 0; i < 4; i++)
                    #pragma unroll
                    for (int j = 0; j < 4; j++)
                        acc[i][j] = __builtin_amdgcn_mfma_f32_16x16x32_bf16(
                            wf[i], hf[j], acc[i][j], 0, 0, 0);
            }
        }
    }
    __syncthreads();   // all conv2 LDS reads done (incl. Bs buf1 = lc wt region)

    // epilogue macro: D(m=oc contiguous 4, n=b) -> smC[b][oc], packed b64 writes
#define EPILOGUE(SOFF, HOFF)                                                  \
    _Pragma("unroll")                                                         \
    for (int i = 0; i < 4; i++) {                                             \
        const int oc0e = i * 16 + fg * 4;                                     \
        const float4 sv = *(const float4*)(prm + (SOFF) + oc0e);              \
        const float4 hv = *(const float4*)(prm + (HOFF) + oc0e);              \
        _Pragma("unroll")                                                     \
        for (int j = 0; j < 4; j++) {                                         \
            const int bi = wv * 64 + j * 16 + fr;                             \
            float v0 = fmaxf(sv.x * acc[i][j][0] + hv.x, 0.f);                \
            float v1 = fmaxf(sv.y * acc[i][j][1] + hv.y, 0.f);                \
            float v2 = fmaxf(sv.z * acc[i][j][2] + hv.z, 0.f);                \
            float v3 = fmaxf(sv.w * acc[i][j][3] + hv.w, 0.f);                \
            uint2 pk; pk.x = pk2(v0, v1); pk.y = pk2(v2, v3);                 \
            *(uint2*)(sm + bi * 72 + oc0e) = pk;                              \
        }                                                                     \
    }

    // conv2 epilogue -> smC [b][oc] stride 72 (own band) + stage lc3 ks0 wts
    EPILOGUE(OFF_S2, OFF_H2)
    *(u16x8*)(sm + 18432 + t * 8) = wr3[0];
    __syncthreads();

    // ---------------- lc3: K=64 (weights from registers) ----------------
    #pragma unroll
    for (int i = 0; i < 4; i++)
        #pragma unroll
        for (int j = 0; j < 4; j++)
            acc[i][j] = (f32x4){0.f, 0.f, 0.f, 0.f};

    #pragma unroll
    for (int ks = 0; ks < 2; ks++) {
        if (ks == 1) {
            __syncthreads();                       // all ks0 weight reads done
            *(u16x8*)(sm + 18432 + t * 8) = wr3[1];
            __syncthreads();
        }
        bf16x8 hf[4], wf[4];
        #pragma unroll
        for (int j = 0; j < 4; j++)
            hf[j] = *(const bf16x8*)(sm + (wv * 64 + j * 16 + fr) * 72 + ks * 32 + fg * 8);
        #pragma unroll
        for (int i = 0; i < 4; i++)
            wf[i] = *(const bf16x8*)(sm + 18432 + ((i * 16 + fr) * 4 + (fg ^ swz4)) * 8);
        #pragma unroll
        for (int i = 0; i < 4; i++)
            #pragma unroll
            for (int j = 0; j < 4; j++)
                acc[i][j] = __builtin_amdgcn_mfma_f32_16x16x32_bf16(
                    wf[i], hf[j], acc[i][j], 0, 0, 0);
    }

    // lc3 epilogue (own band; own-band reads already consumed)
    EPILOGUE(OFF_S3, OFF_H3)
    __syncthreads();                               // lc3 ks1 weight reads done
    *(u16x8*)(sm + 18432 + t * 8) = wr4[0];
    __syncthreads();

    // ---------------- lc4: K=64 ----------------
    #pragma unroll
    for (int i = 0; i < 4; i++)
        #pragma unroll
        for (int j = 0; j < 4; j++)
            acc[i][j] = (f32x4){0.f, 0.f, 0.f, 0.f};

    #pragma unroll
    for (int ks = 0; ks < 2; ks++) {
        if (ks == 1) {
            __syncthreads();
            *(u16x8*)(sm + 18432 + t * 8) = wr4[1];
            __syncthreads();
        }
        bf16x8 hf[4], wf[4];
        #pragma unroll
        for (int j = 0; j < 4; j++)
            hf[j] = *(const bf16x8*)(sm + (wv * 64 + j * 16 + fr) * 72 + ks * 32 + fg * 8);
        #pragma unroll
        for (int i = 0; i < 4; i++)
            wf[i] = *(const bf16x8*)(sm + 18432 + ((i * 16 + fr) * 4 + (fg ^ swz4)) * 8);
        #pragma unroll
        for (int i = 0; i < 4; i++)
            #pragma unroll
            for (int j = 0; j < 4; j++)
                acc[i][j] = __builtin_amdgcn_mfma_f32_16x16x32_bf16(
                    wf[i], hf[j], acc[i][j], 0, 0, 0);
    }

    // lc4 epilogue -> smC, then barrier, then coalesced bufA write (all bands)
    EPILOGUE(OFF_S4, OFF_H4)
#undef EPILOGUE
    __syncthreads();

    const int wrow = t >> 3, wc0 = (t & 7) * 8;
    #pragma unroll
    for (int pass = 0; pass < 8; pass++) {
        const int row = wrow + pass * 32;
        *(uint4*)(bufA + (size_t)(m0 + row) * 8192 + p * 64 + wc0) =
            *(const uint4*)(sm + row * 72 + wc0);
    }
}

// ---------------------------------------------------------------------------
// MFMA GEMM: out[M][N] = relu(s*(A.W^T)+shift), bf16.
// BM=128, BN=64, BK=64.  4 waves 2x2, wave tile 64x32, 16 MFMA per barrier.
// XOR-swizzled chunks -> coalesced gll staging + free 2-way b128 frag reads.
// 1-deep dbuf, 1 barrier per k-step.  48 KiB LDS.  (m97-plateau; done.)
// ---------------------------------------------------------------------------
__global__ __launch_bounds__(256) void gemm_mfma(
    const bf16_t* __restrict__ A, const bf16_t* __restrict__ W,
    const float* __restrict__ prm, int sc_off, int sh_off,
    bf16_t* __restrict__ out, int K, int N)
{
    __shared__ bf16_t sm[24576];
    const int t    = threadIdx.x;
    const int lane = t & 63;
    const int wv   = t >> 6;
    const int wr   = wv >> 1, wc = wv & 1;
    const int m0   = blockIdx.x * 128, n0 = blockIdx.y * 64;

    const int fr = lane & 15;
    const int fg = lane >> 4;
    const int swz8 = fr & 7;

    const bf16_t* srcA[4]; bf16_t* dstA[4];
    #pragma unroll
    for (int u = 0; u < 4; u++) {
        const int c = t + 256 * u;
        const int row = c >> 3;
        const int g = (c & 7) ^ (row & 7);
        srcA[u] = A + (size_t)(m0 + row) * K + g * 8;
        dstA[u] = sm + c * 8;
    }
    const bf16_t* srcB[2]; bf16_t* dstB[2];
    #pragma unroll
    for (int u = 0; u < 2; u++) {
        const int c = t + 256 * u;
        const int row = c >> 3;
        const int g = (c & 7) ^ (row & 7);
        srcB[u] = W + (size_t)(n0 + row) * K + g * 8;
        dstB[u] = sm + 16384 + c * 8;
    }

    f32x4 acc[4][2];
    #pragma unroll
    for (int i = 0; i < 4; i++)
        #pragma unroll
        for (int j = 0; j < 2; j++)
            acc[i][j] = (f32x4){0.f, 0.f, 0.f, 0.f};

    const int KS = K >> 6;

    #pragma unroll
    for (int u = 0; u < 4; u++) stg16(srcA[u], dstA[u]);
    #pragma unroll
    for (int u = 0; u < 2; u++) stg16(srcB[u], dstB[u]);

    for (int ks = 0; ks < KS; ks++) {
        const int cur = ks & 1;
        __syncthreads();
        if (ks + 1 < KS) {
            const int nb = cur ^ 1;
            const int kk = (ks + 1) << 6;
            #pragma unroll
            for (int u = 0; u < 4; u++) stg16(srcA[u] + kk, dstA[u] + nb * 8192);
            #pragma unroll
            for (int u = 0; u < 2; u++) stg16(srcB[u] + kk, dstB[u] + nb * 4096);
        }
        const bf16_t* Ab = sm + cur * 8192;
        const bf16_t* Bb = sm + 16384 + cur * 4096;
        bf16x8 af[4][2], bf2[2][2];
        #pragma unroll
        for (int i = 0; i < 4; i++)
            #pragma unroll
            for (int hh = 0; hh < 2; hh++) {
                const int r = wr * 64 + i * 16 + fr;
                const int g = hh * 4 + fg;
                af[i][hh] = *(const bf16x8*)(Ab + (r * 8 + (g ^ swz8)) * 8);
            }
        #pragma unroll
        for (int j = 0; j < 2; j++)
            #pragma unroll
            for (int hh = 0; hh < 2; hh++) {
                const int r = wc * 32 + j * 16 + fr;
                const int g = hh * 4 + fg;
                bf2[j][hh] = *(const bf16x8*)(Bb + (r * 8 + (g ^ swz8)) * 8);
            }
        #pragma unroll
        for (int hh = 0; hh < 2; hh++)
            #pragma unroll
            for (int i = 0; i < 4; i++)
                #pragma unroll
                for (int j = 0; j < 2; j++)
                    acc[i][j] = __builtin_amdgcn_mfma_f32_16x16x32_bf16(
                        af[i][hh], bf2[j][hh], acc[i][j], 0, 0, 0);
    }

    const float s    = prm[sc_off];
    const int   orow = fg * 4;
    const int   ocol = fr;
    #pragma unroll
    for (int j = 0; j < 2; j++) {
        const int n  = n0 + wc * 32 + j * 16 + ocol;
        const float sh = prm[sh_off + n];
        #pragma unroll
        for (int i = 0; i < 4; i++) {
            const int mb = m0 + wr * 64 + i * 16 + orow;
            #pragma unroll
            for (int r = 0; r < 4; r++) {
                float v = fmaxf(s * acc[i][j][r] + sh, 0.f);
                out[(size_t)(mb + r) * N + n] = f2b(v);
            }
        }
    }
}

// ---------------------------------------------------------------------------
// fc8: out[b][n] = h[b][:] . w8[n][:] + b8[n]   (N=8, K=128), h is bf16
// ---------------------------------------------------------------------------
__global__ __launch_bounds__(256) void fc8_kernel(
    const bf16_t* __restrict__ h, const float* __restrict__ prm,
    void* __restrict__ out, int c0)
{
    __shared__ float wsm[8 * 129];
    const int t = threadIdx.x;
    for (int i = t; i < 1024; i += 256) {
        int n = i >> 7, k = i & 127;
        wsm[n * 129 + k] = prm[OFF_W8 + i];
    }
    __syncthreads();
    const int isf = prm[OFF_FLAG] > 0.5f;
    const int bl = t >> 3, n = t & 7;
    const int b = c0 + blockIdx.x * 32 + bl;
    const bf16_t* hb = h + (size_t)(blockIdx.x * 32 + bl) * 128;
    float acc = prm[OFF_B8 + n];
    for (int k = 0; k < 128; k++) acc += b2f(hb[k]) * wsm[n * 129 + k];
    if (isf) ((float*)out)[(size_t)b * 8 + n] = acc;
    else     ((bf16_t*)out)[(size_t)b * 8 + n] = f2b(acc);
}

// ---------------------------------------------------------------------------
extern "C" void kernel_launch(void* const* d_in, const int* in_sizes, int n_in,
                              void* d_out, int out_size, void* d_ws, size_t ws_size,
                              hipStream_t stream)
{
    const void* x    = d_in[0];
    const void* bn0p = d_in[1];
    const void* w1   = d_in[2];
    const void* b1   = d_in[3];
    const void* bn1p = d_in[4];
    const void* w2   = d_in[5];
    const void* b2c  = d_in[6];
    const void* bn2p = d_in[7];
    const void* w3   = d_in[8];
    const void* bn3p = d_in[9];
    const void* w4   = d_in[10];
    const void* bn4p = d_in[11];
    const void* w5   = d_in[12];
    const void* b5   = d_in[13];
    const void* bn5p = d_in[14];
    const void* w6   = d_in[15];
    const void* b6   = d_in[16];
    const void* bn6p = d_in[17];
    const void* w7   = d_in[18];
    const void* b7   = d_in[19];
    const void* bn7p = d_in[20];
    const void* w8   = d_in[21];
    const void* b8   = d_in[22];

    char* base = (char*)d_ws;
    float*  prm = (float*)(base + 0);            //    16384 B
    bf16_t* w2p = (bf16_t*)(base + 16384);       //    73728 B
    bf16_t* w3p = (bf16_t*)(base + 90112);       //  1048576 B
    bf16_t* w4p = (bf16_t*)(base + 1138688);     //  1048576 B
    bf16_t* w5p = (bf16_t*)(base + 2187264);     //  8388608 B
    bf16_t* w6b = (bf16_t*)(base + 10575872);    //   524288 B
    bf16_t* w7b = (bf16_t*)(base + 11100160);    //   131072 B
    char*   acts = base + 11231232;

    const int B = 8192;
    const size_t FIXED = 11231232ull;

    fold_params_kernel<<<1, 256, 0, stream>>>(
        x, bn0p, w1, b1, bn1p, b2c, bn2p, bn3p, bn4p,
        b5, bn5p, b6, bn6p, b7, bn7p, w8, b8, prm);
    setup_kernel<<<21904, 256, 0, stream>>>(
        w2, w3, w4, w5, w6, w7, w2p, w3p, w4p, w5p, w6b, w7b, prm);

    const int Bf = 4096;
    const size_t FULL_NEED = FIXED + (size_t)Bf * 16384ull + (size_t)B * 18688ull;

    if (ws_size >= FULL_NEED) {
        bf16_t* c1   = (bf16_t*)acts;                    // [128][Bf][64]
        bf16_t* bufA = c1 + (size_t)Bf * 8192;           // [B][8192]
        bf16_t* bufC = bufA + (size_t)B * 8192;          // [B][512]
        bf16_t* bufD = bufC + (size_t)B * 512;           // [B][512]
        bf16_t* bufE = bufD + (size_t)B * 512;           // [B][128]

        for (int c0 = 0; c0 < B; c0 += Bf) {
            conv1_kernel<<<Bf / 4, 256, 0, stream>>>(x, prm, c1, Bf, c0);
            fused_mfma_kernel<<<dim3(Bf / 256, 128), 256, 0, stream>>>(
                c1, w2p, w3p, w4p, prm, bufA + (size_t)c0 * 8192, Bf);
        }
        gemm_mfma<<<dim3(B / 128, 8), 256, 0, stream>>>(
            bufA, w5p, prm, OFF_SC5, OFF_H5, bufC, 8192, 512);
        gemm_mfma<<<dim3(B / 128, 8), 256, 0, stream>>>(
            bufC, w6b, prm, OFF_SC6, OFF_H6, bufD, 512, 512);
        gemm_mfma<<<dim3(B / 128, 2), 256, 0, stream>>>(
            bufD, w7b, prm, OFF_SC7, OFF_H7, bufE, 512, 128);
        fc8_kernel<<<B / 32, 256, 0, stream>>>(bufE, prm, d_out, 0);
    } else {
        size_t avail = (ws_size > FIXED) ? (ws_size - FIXED) : 0;
        int Bc = 8192;
        while (Bc > 256 && (size_t)Bc * 35072ull > avail) Bc >>= 1;

        bf16_t* c1   = (bf16_t*)acts;
        bf16_t* bufA = c1 + (size_t)Bc * 8192;
        bf16_t* bufC = bufA + (size_t)Bc * 8192;
        bf16_t* bufD = bufC + (size_t)Bc * 512;
        bf16_t* bufE = bufD + (size_t)Bc * 512;

        for (int c0 = 0; c0 < B; c0 += Bc) {
            conv1_kernel<<<Bc / 4, 256, 0, stream>>>(x, prm, c1, Bc, c0);
            fused_mfma_kernel<<<dim3(Bc / 256, 128), 256, 0, stream>>>(
                c1, w2p, w3p, w4p, prm, bufA, Bc);
            gemm_mfma<<<dim3(Bc / 128, 8), 256, 0, stream>>>(
                bufA, w5p, prm, OFF_SC5, OFF_H5, bufC, 8192, 512);
            gemm_mfma<<<dim3(Bc / 128, 8), 256, 0, stream>>>(
                bufC, w6b, prm, OFF_SC6, OFF_H6, bufD, 512, 512);
            gemm_mfma<<<dim3(Bc / 128, 2), 256, 0, stream>>>(
                bufD, w7b, prm, OFF_SC7, OFF_H7, bufE, 512, 128);
            fc8_kernel<<<Bc / 32, 256, 0, stream>>>(bufE, prm, d_out, c0);
        }
    }
}